// Round 20
// baseline (285.040 us; speedup 1.0000x reference)
//
#include <hip/hip_runtime.h>
#include <hip/hip_bf16.h>
#include <hip/hip_fp16.h>

#define NEG_SLOPE 0.2f
#define LOG_R 10
#define RPB (1 << LOG_R)      // dsts per coarse bucket
#define EPB 4096              // edges per bucket_pass block
#define CAPB 24576            // fine_sort LDS staging entries

typedef __attribute__((ext_vector_type(4))) float f32x4;
typedef __attribute__((ext_vector_type(2))) float f32x2;
typedef __attribute__((ext_vector_type(8))) short s16x8;

static __device__ __forceinline__ unsigned pkbf(float a, float b) {
    unsigned ua = __float_as_uint(a);
    ua = (ua + 0x7FFFu + ((ua >> 16) & 1u)) >> 16;
    unsigned ub = __float_as_uint(b);
    ub = (ub + 0x7FFFu + ((ub >> 16) & 1u)) & 0xFFFF0000u;
    return (ua & 0xFFFFu) | ub;
}
static __device__ __forceinline__ unsigned short bf1(float a) {
    unsigned ua = __float_as_uint(a);
    return (unsigned short)((ua + 0x7FFFu + ((ua >> 16) & 1u)) >> 16);
}
static __device__ __forceinline__ float bflo(unsigned u) { return __uint_as_float(u << 16); }
static __device__ __forceinline__ float bfhi(unsigned u) { return __uint_as_float(u & 0xFFFF0000u); }

// both MHA weight-combines in one kernel
__global__ __launch_bounds__(256) void mha_combine2(
    const float* __restrict__ iw1, const float* __restrict__ ib1,
    const float* __restrict__ ow1, const float* __restrict__ ob1,
    const float* __restrict__ iw2, const float* __restrict__ ib2,
    const float* __restrict__ ow2, const float* __restrict__ ob2,
    float* __restrict__ cw1, float* __restrict__ cb1,
    float* __restrict__ cw2, float* __restrict__ cb2)
{
    int idx = blockIdx.x * blockDim.x + threadIdx.x;
    int set = idx >> 14;
    int local = idx & 16383;
    int o = local >> 7, i = local & 127;
    const float* in_w  = set ? iw2 : iw1;
    const float* in_b  = set ? ib2 : ib1;
    const float* out_w = set ? ow2 : ow1;
    const float* out_b = set ? ob2 : ob1;
    float* combW = set ? cw2 : cw1;
    float* combb = set ? cb2 : cb1;
    float a = 0.f;
    for (int k = 0; k < 128; ++k)
        a = fmaf(out_w[o * 128 + k], in_w[(256 + k) * 128 + i], a);
    combW[local] = a;
    if (i == 0) {
        float b = out_b[o];
        for (int k = 0; k < 128; ++k)
            b = fmaf(out_w[o * 128 + k], in_b[256 + k], b);
        combb[o] = b;
    }
}

// pack five 128x128 f32 weight matrices -> bf16 pairs [5][128][64]
__global__ __launch_bounds__(256) void wpack5(
    const float* __restrict__ cw1, const float* __restrict__ cw2,
    const float* __restrict__ g1w, const float* __restrict__ g2xw,
    const float* __restrict__ g2yw, unsigned* __restrict__ wp)
{
    int i = blockIdx.x * 256 + threadIdx.x;
    if (i >= 5 * 8192) return;
    int m = i >> 13, loc = i & 8191;
    const float* src = (m == 0) ? cw1 : (m == 1) ? cw2 : (m == 2) ? g1w
                     : (m == 3) ? g2xw : g2yw;
    float2 f = ((const float2*)src)[loc];
    wp[i] = pkbf(f.x, f.y);
}

// fc weight prep: f32 [40][384] -> packed bf16 [48][384] (rows 40..47 zero)
__global__ __launch_bounds__(256) void fcw_prep(
    const float* __restrict__ fcw, unsigned* __restrict__ wbf)
{
    int i = blockIdx.x * 256 + threadIdx.x;
    if (i >= 48 * 192) return;
    unsigned v = 0;
    if (i < 40 * 192) {
        float2 f = ((const float2*)fcw)[i];
        v = pkbf(f.x, f.y);
    }
    wbf[i] = v;
}

// Fused two-graph MFMA GEMM: 4 INDEPENDENT waves per 256-thr block,
// each wave owns 16 rows + a private 4 KB LDS quarter. W fragments read
// from pre-packed bf16 global (L1/L2-hot).
// HFP8: store h as fp8 e4m3; else packed bf16.
// ao*: optional packed-bf16 copy of the staged A input (saves x->bf16 for fc).
template<bool ABF, bool HFP8>
__global__ __launch_bounds__(256) void gemm_mfma2(
    const void* __restrict__ A0, const void* __restrict__ A1,
    const unsigned* __restrict__ Wp0, const unsigned* __restrict__ Wp1,
    const float* __restrict__ bias0, const float* __restrict__ bias1,
    const float* __restrict__ as0, const float* __restrict__ ad0,
    const float* __restrict__ as1, const float* __restrict__ ad1,
    void* __restrict__ h0, void* __restrict__ h1,
    float* __restrict__ ss0, float* __restrict__ sd0,
    float* __restrict__ ss1, float* __restrict__ sd1,
    unsigned* __restrict__ ao0, unsigned* __restrict__ ao1,
    int n, int half)
{
    __shared__ unsigned xl[4][16 * 64];    // per-wave A tile, 4 KB each

    int b = blockIdx.x;
    const void* Ain; const unsigned* Wp; const float *bias, *asrc, *adst;
    void* hbs; float *ssrc, *sdst; unsigned* aout;
    if (b < half) { Ain = A0; Wp = Wp0; bias = bias0; asrc = as0; adst = ad0; hbs = h0; ssrc = ss0; sdst = sd0; aout = ao0; }
    else { b -= half; Ain = A1; Wp = Wp1; bias = bias1; asrc = as1; adst = ad1; hbs = h1; ssrc = ss1; sdst = sd1; aout = ao1; }

    const int t = threadIdx.x;
    const int wv = t >> 6;
    const int lane = t & 63;
    const int row0 = b * 64 + wv * 16;

    // stage A: 256 slots per wave, 4 per lane (wave-synchronous, no barrier)
#pragma unroll
    for (int i = 0; i < 4; ++i) {
        int q = lane + i * 64;
        int r = q >> 4, sl = q & 15;
        int gr = row0 + r; if (gr >= n) gr = n - 1;
        unsigned p0, p1, p2, p3;
        if (ABF) {
            uint4 v = ((const uint4*)Ain)[(size_t)gr * 16 + sl];
            p0 = v.x; p1 = v.y; p2 = v.z; p3 = v.w;
        } else {
            float4 a = ((const float4*)Ain)[(size_t)gr * 32 + sl * 2];
            float4 bb = ((const float4*)Ain)[(size_t)gr * 32 + sl * 2 + 1];
            p0 = pkbf(a.x, a.y); p1 = pkbf(a.z, a.w);
            p2 = pkbf(bb.x, bb.y); p3 = pkbf(bb.z, bb.w);
            if (aout) ((uint4*)aout)[(size_t)gr * 16 + sl] = make_uint4(p0, p1, p2, p3);
        }
        int dsl = sl ^ (r & 7);
        *(uint4*)&xl[wv][r * 64 + dsl * 4] = make_uint4(p0, p1, p2, p3);
    }
    __syncthreads();

    const int c = lane & 15, q4 = lane >> 4;
    f32x4 acc[8];
#pragma unroll
    for (int nt = 0; nt < 8; ++nt) acc[nt] = (f32x4){0.f, 0.f, 0.f, 0.f};

#pragma unroll
    for (int s = 0; s < 4; ++s) {
        int gslot = s * 4 + q4;
        int slotA = gslot ^ (c & 7);
        s16x8 af = *(const s16x8*)&xl[wv][c * 64 + slotA * 4];
        const unsigned* wb = Wp + (size_t)c * 64 + gslot * 4;
#pragma unroll
        for (int nt = 0; nt < 8; ++nt) {
            s16x8 bfr = *(const s16x8*)(wb + (size_t)nt * 1024);   // (nt*16+c)*64
            acc[nt] = __builtin_amdgcn_mfma_f32_16x16x32_bf16(af, bfr, acc[nt], 0, 0, 0);
        }
    }

    float bv[8], as8[8], ad8[8];
#pragma unroll
    for (int nt = 0; nt < 8; ++nt) {
        bv[nt]  = bias ? bias[nt * 16 + c] : 0.f;
        as8[nt] = asrc ? asrc[nt * 16 + c] : 0.f;
        ad8[nt] = asrc ? adst[nt * 16 + c] : 0.f;
    }
    float ps[4] = {0.f, 0.f, 0.f, 0.f}, pd[4] = {0.f, 0.f, 0.f, 0.f};
    const int grow0 = row0 + q4 * 4;
#pragma unroll
    for (int nt = 0; nt < 8; ++nt) {
#pragma unroll
        for (int j = 0; j < 4; ++j) {
            float val = acc[nt][j] + bv[nt];
            if (grow0 + j < n) {
                if (HFP8) {
                    unsigned b8 = (unsigned)__builtin_amdgcn_cvt_pk_fp8_f32(val, val, 0, false);
                    ((unsigned char*)hbs)[(size_t)(grow0 + j) * 128 + nt * 16 + c] = (unsigned char)b8;
                } else {
                    ((unsigned short*)hbs)[(size_t)(grow0 + j) * 128 + nt * 16 + c] = bf1(val);
                }
            }
            ps[j] = fmaf(val, as8[nt], ps[j]);
            pd[j] = fmaf(val, ad8[nt], pd[j]);
        }
    }
    if (asrc) {
#pragma unroll
        for (int j = 0; j < 4; ++j) {
            float a = ps[j], bb = pd[j];
#pragma unroll
            for (int o = 1; o < 16; o <<= 1) {
                a += __shfl_xor(a, o);
                bb += __shfl_xor(bb, o);
            }
            if (c == 0 && grow0 + j < n) { ssrc[grow0 + j] = a; sdst[grow0 + j] = bb; }
        }
    }
}

// ---------------- CSR build: two-level bucket sort ----------------

__global__ __launch_bounds__(256) void hist_bucket2(
    const int* __restrict__ eix, const int* __restrict__ eiy, int E, int n,
    int* __restrict__ bcx, int* __restrict__ bcy, int half)
{
    __shared__ int lh[64];
    int gb = blockIdx.x;
    const int* ei = eix; int* bc = bcx;
    if (gb >= half) { gb -= half; ei = eiy; bc = bcy; }
    int t = threadIdx.x;
    int ET = E + n;
    int nbk = (n + RPB - 1) >> LOG_R;
    for (int i = t; i < nbk; i += 256) lh[i] = 0;
    __syncthreads();
    for (int e = gb * 256 + t; e < ET; e += half * 256) {
        int d = (e < E) ? ei[E + e] : (e - E);
        atomicAdd(&lh[d >> LOG_R], 1);
    }
    __syncthreads();
    if (t < nbk) atomicAdd(&bc[t], lh[t]);
}

__global__ void bscan(
    const int* __restrict__ bcx, const int* __restrict__ bcy, int nbk,
    int* __restrict__ bbx, int* __restrict__ bby,
    int* __restrict__ curx, int* __restrict__ cury,
    int* __restrict__ offx_n, int* __restrict__ offy_n)
{
    int w = threadIdx.x >> 6, lane = threadIdx.x & 63;
    if (w > 1) return;
    const int* bc = w ? bcy : bcx;
    int* bb  = w ? bby : bbx;
    int* cur = w ? cury : curx;
    int* offn = w ? offy_n : offx_n;
    int c = (lane < nbk) ? bc[lane] : 0;
    int v = c;
#pragma unroll
    for (int o = 1; o < 64; o <<= 1) {
        int u = __shfl_up(v, o);
        if (lane >= o) v += u;
    }
    int excl = v - c;
    if (lane < nbk) { bb[lane] = excl; cur[lane] = excl; }
    if (lane == 63) { bb[nbk] = v; *offn = v; }
}

// pass A: bucket edges by dst>>LOG_R; per-block LDS sort + contiguous run flush.
__global__ __launch_bounds__(256) void bucket_pass(
    const int* __restrict__ eix, const int* __restrict__ eiy, int E, int n,
    int* __restrict__ curx, int* __restrict__ cury,
    unsigned* __restrict__ pkx, unsigned* __restrict__ pky, int half)
{
    __shared__ int lhist[64], lbase[64], gbase[64], lpos[64];
    __shared__ unsigned stg[EPB];
    __shared__ int gidx[EPB];
    int gb = blockIdx.x;
    const int* ei = eix; int* bcur = curx; unsigned* pk = pkx;
    if (gb >= half) { gb -= half; ei = eiy; bcur = cury; pk = pky; }
    const int t = threadIdx.x;
    const int ET = E + n;
    const int nbk = (n + RPB - 1) >> LOG_R;   // must be <= 64
    const int base = gb * EPB;

    for (int i = t; i < nbk; i += 256) lhist[i] = 0;
    __syncthreads();

    unsigned mypk[16];
    int myb[16];
#pragma unroll
    for (int k = 0; k < 16; ++k) {
        int e = base + k * 256 + t;
        if (e < ET) {
            int s, d;
            if (e < E) { s = ei[e]; d = ei[E + e]; }
            else       { s = e - E; d = e - E; }
            myb[k] = d >> LOG_R;
            mypk[k] = ((unsigned)s << LOG_R) | (unsigned)(d & (RPB - 1));
            atomicAdd(&lhist[myb[k]], 1);
        } else myb[k] = -1;
    }
    __syncthreads();

    if (t < 64) {
        int c = (t < nbk) ? lhist[t] : 0;
        int v = c;
#pragma unroll
        for (int o = 1; o < 64; o <<= 1) {
            int u = __shfl_up(v, o);
            if (t >= o) v += u;
        }
        int excl = v - c;
        if (t < nbk) {
            lbase[t] = excl;
            lpos[t] = excl;
            gbase[t] = c ? atomicAdd(&bcur[t], c) : 0;
        }
    }
    __syncthreads();

#pragma unroll
    for (int k = 0; k < 16; ++k) {
        if (myb[k] >= 0) {
            int p = atomicAdd(&lpos[myb[k]], 1);
            stg[p] = mypk[k];
            gidx[p] = gbase[myb[k]] + (p - lbase[myb[k]]);
        }
    }
    __syncthreads();

    int tot = lbase[nbk - 1] + lhist[nbk - 1];
    for (int i = t; i < tot; i += 256) pk[gidx[i]] = stg[i];
}

// pass B: one block per bucket; per-dst hist + scan (produces off[]), then
// in-LDS scatter and coalesced ushort writeback.
__global__ __launch_bounds__(256) void fine_sort(
    const unsigned* __restrict__ pkx, const unsigned* __restrict__ pky,
    const int* __restrict__ bbx, const int* __restrict__ bby,
    int* __restrict__ offx, int* __restrict__ offy,
    unsigned short* __restrict__ csx, unsigned short* __restrict__ csy,
    int n, int half)
{
    __shared__ int cur[RPB];
    __shared__ int ws[256];
    __shared__ unsigned short outs[CAPB];
    int gb = blockIdx.x;
    const unsigned* pk; const int* bb; int* off; unsigned short* cs;
    if (gb < half) { pk = pkx; bb = bbx; off = offx; cs = csx; }
    else { gb -= half; pk = pky; bb = bby; off = offy; cs = csy; }
    const int t = threadIdx.x;
    const int d0 = gb << LOG_R;
    const int nd = min(RPB, n - d0);
    const int base = bb[gb];
    const int sz = bb[gb + 1] - base;

    for (int i = t; i < RPB; i += 256) cur[i] = 0;
    __syncthreads();
    for (int i = t; i < sz; i += 256)
        atomicAdd(&cur[pk[base + i] & (RPB - 1)], 1);
    __syncthreads();

    int c0 = cur[t * 4], c1 = cur[t * 4 + 1], c2 = cur[t * 4 + 2], c3 = cur[t * 4 + 3];
    int s = c0 + c1 + c2 + c3;
    ws[t] = s; __syncthreads();
    for (int o = 1; o < 256; o <<= 1) {
        int a = (t >= o) ? ws[t - o] : 0;
        __syncthreads();
        ws[t] += a;
        __syncthreads();
    }
    int ex = ws[t] - s;
    int e0 = ex, e1 = ex + c0, e2 = e1 + c1, e3 = e2 + c2;
    cur[t * 4] = e0; cur[t * 4 + 1] = e1; cur[t * 4 + 2] = e2; cur[t * 4 + 3] = e3;
    int i0 = t * 4;
    if (i0     < nd) off[d0 + i0]     = base + e0;
    if (i0 + 1 < nd) off[d0 + i0 + 1] = base + e1;
    if (i0 + 2 < nd) off[d0 + i0 + 2] = base + e2;
    if (i0 + 3 < nd) off[d0 + i0 + 3] = base + e3;
    __syncthreads();

    if (sz <= CAPB) {
        for (int i = t; i < sz; i += 256) {
            unsigned p = pk[base + i];
            int pos = atomicAdd(&cur[p & (RPB - 1)], 1);
            outs[pos] = (unsigned short)(p >> LOG_R);
        }
        __syncthreads();
        for (int i = t; i < sz; i += 256) cs[base + i] = outs[i];
    } else {
        for (int i = t; i < sz; i += 256) {
            unsigned p = pk[base + i];
            int pos = atomicAdd(&cur[p & (RPB - 1)], 1);
            cs[base + pos] = (unsigned short)(p >> LOG_R);
        }
    }
}

// ---------------- fused two-graph GAT aggregation ----------------
// h stored as fp8 e4m3 (128 B/row = 16 lanes x 8 B). FOUR nodes per wave;
// stg padded to 34 entries/node so the 4 quarter-broadcasts hit distinct banks.
__global__ __launch_bounds__(256) void gat_aggregate2(
    const int* __restrict__ off0, const unsigned short* __restrict__ cs0,
    const float* __restrict__ ss0, const float* __restrict__ sd0,
    const unsigned char* __restrict__ hb0, const float* __restrict__ bias0,
    unsigned* __restrict__ out0,
    const int* __restrict__ off1, const unsigned short* __restrict__ cs1,
    const float* __restrict__ ss1, const float* __restrict__ sd1,
    const unsigned char* __restrict__ hb1, const float* __restrict__ bias1,
    unsigned* __restrict__ out1,
    int n, int relu, int half)
{
    __shared__ uint2 stg[4][4][34];
    int b = blockIdx.x;
    const int *off; const unsigned short *csrc; const float *ssrc, *sdst, *bias;
    const unsigned char* hb; unsigned* outu;
    if (b < half) { off = off0; csrc = cs0; ssrc = ss0; sdst = sd0; hb = hb0; bias = bias0; outu = out0; }
    else { b -= half; off = off1; csrc = cs1; ssrc = ss1; sdst = sd1; hb = hb1; bias = bias1; outu = out1; }

    const int w = threadIdx.x >> 6;          // wave in block
    const int lane = threadIdx.x & 63;
    const int qw = lane >> 4;                // quarter-wave = node slot
    const int l16 = lane & 15;
    int node = b * 16 + w * 4 + qw;
    const int valid = node < n;
    if (node >= n) node = n - 1;             // clamp (writes guarded)
    const int p0 = off[node], p1 = off[node + 1];
    const int deg = p1 - p0;
    const float sd = sdst[node];

    // pass A: each lane handles neighbors l16 and l16+16 (exp directly, no max)
    unsigned s0 = 0, s1 = 0;
    float e0 = 0.f, e1 = 0.f;
    if (l16 < deg) {
        s0 = csrc[p0 + l16];
        float v = ssrc[s0] + sd;
        v = (v > 0.f) ? v : NEG_SLOPE * v;
        e0 = __expf(v);
    }
    if (l16 + 16 < deg) {
        s1 = csrc[p0 + 16 + l16];
        float v = ssrc[s1] + sd;
        v = (v > 0.f) ? v : NEG_SLOPE * v;
        e1 = __expf(v);
    }
    float ssum = e0 + e1;
    for (int p = p0 + 32 + l16; p < p1; p += 16) {    // rare deg>32 overflow
        int s = csrc[p];
        float v = ssrc[s] + sd;
        v = (v > 0.f) ? v : NEG_SLOPE * v;
        ssum += __expf(v);
    }
#pragma unroll
    for (int o = 8; o; o >>= 1) ssum += __shfl_xor(ssum, o);

    // stage (src<<7, e) for 32 slots per node; padding entries have e=0
    stg[w][qw][l16]      = make_uint2(s0 << 7, __float_as_uint(e0));
    stg[w][qw][l16 + 16] = make_uint2(s1 << 7, __float_as_uint(e1));

    const unsigned clo = (unsigned)l16 * 8u;          // byte offset: 8 fp8 cols
    float a0 = 0.f, a1 = 0.f, a2 = 0.f, a3 = 0.f;
    float a4 = 0.f, a5 = 0.f, a6 = 0.f, a7 = 0.f;

    int jcap = deg < 32 ? deg : 32;
    int j = 0;
    for (; j + 8 <= jcap; j += 8) {
        uint2 q[8];
#pragma unroll
        for (int k = 0; k < 8; ++k) q[k] = stg[w][qw][j + k];   // broadcast per quarter
        uint2 u[8];
#pragma unroll
        for (int k = 0; k < 8; ++k)
            u[k] = *(const uint2*)(hb + (size_t)(q[k].x | clo));
#pragma unroll
        for (int k = 0; k < 8; ++k) {
            float e = __uint_as_float(q[k].y);
            f32x2 f0 = __builtin_amdgcn_cvt_pk_f32_fp8((int)u[k].x, false);
            f32x2 f1 = __builtin_amdgcn_cvt_pk_f32_fp8((int)u[k].x, true);
            f32x2 f2 = __builtin_amdgcn_cvt_pk_f32_fp8((int)u[k].y, false);
            f32x2 f3 = __builtin_amdgcn_cvt_pk_f32_fp8((int)u[k].y, true);
            a0 = fmaf(e, f0[0], a0); a1 = fmaf(e, f0[1], a1);
            a2 = fmaf(e, f1[0], a2); a3 = fmaf(e, f1[1], a3);
            a4 = fmaf(e, f2[0], a4); a5 = fmaf(e, f2[1], a5);
            a6 = fmaf(e, f3[0], a6); a7 = fmaf(e, f3[1], a7);
        }
    }
    for (; j < jcap; ++j) {
        uint2 q = stg[w][qw][j];
        uint2 u = *(const uint2*)(hb + (size_t)(q.x | clo));
        float e = __uint_as_float(q.y);
        f32x2 f0 = __builtin_amdgcn_cvt_pk_f32_fp8((int)u.x, false);
        f32x2 f1 = __builtin_amdgcn_cvt_pk_f32_fp8((int)u.x, true);
        f32x2 f2 = __builtin_amdgcn_cvt_pk_f32_fp8((int)u.y, false);
        f32x2 f3 = __builtin_amdgcn_cvt_pk_f32_fp8((int)u.y, true);
        a0 = fmaf(e, f0[0], a0); a1 = fmaf(e, f0[1], a1);
        a2 = fmaf(e, f1[0], a2); a3 = fmaf(e, f1[1], a3);
        a4 = fmaf(e, f2[0], a4); a5 = fmaf(e, f2[1], a5);
        a6 = fmaf(e, f3[0], a6); a7 = fmaf(e, f3[1], a7);
    }
    for (int p = p0 + 32; p < p1; ++p) {              // rare deg>32 overflow
        int s = csrc[p];
        float v = ssrc[s] + sd;
        v = (v > 0.f) ? v : NEG_SLOPE * v;
        float e = __expf(v);
        uint2 u = *(const uint2*)(hb + (((size_t)s << 7) | clo));
        f32x2 f0 = __builtin_amdgcn_cvt_pk_f32_fp8((int)u.x, false);
        f32x2 f1 = __builtin_amdgcn_cvt_pk_f32_fp8((int)u.x, true);
        f32x2 f2 = __builtin_amdgcn_cvt_pk_f32_fp8((int)u.y, false);
        f32x2 f3 = __builtin_amdgcn_cvt_pk_f32_fp8((int)u.y, true);
        a0 = fmaf(e, f0[0], a0); a1 = fmaf(e, f0[1], a1);
        a2 = fmaf(e, f1[0], a2); a3 = fmaf(e, f1[1], a3);
        a4 = fmaf(e, f2[0], a4); a5 = fmaf(e, f2[1], a5);
        a6 = fmaf(e, f3[0], a6); a7 = fmaf(e, f3[1], a7);
    }

    float inv = 1.f / (ssum + 1e-16f);
    float4 bva = ((const float4*)bias)[l16 * 2];
    float4 bvb = ((const float4*)bias)[l16 * 2 + 1];
    float o0 = fmaf(a0, inv, bva.x);
    float o1 = fmaf(a1, inv, bva.y);
    float o2 = fmaf(a2, inv, bva.z);
    float o3 = fmaf(a3, inv, bva.w);
    float o4 = fmaf(a4, inv, bvb.x);
    float o5 = fmaf(a5, inv, bvb.y);
    float o6 = fmaf(a6, inv, bvb.z);
    float o7 = fmaf(a7, inv, bvb.w);
    if (relu) {
        o0 = fmaxf(o0, 0.f); o1 = fmaxf(o1, 0.f);
        o2 = fmaxf(o2, 0.f); o3 = fmaxf(o3, 0.f);
        o4 = fmaxf(o4, 0.f); o5 = fmaxf(o5, 0.f);
        o6 = fmaxf(o6, 0.f); o7 = fmaxf(o7, 0.f);
    }
    if (valid)
        ((uint4*)(outu + (size_t)node * 64))[l16] =
            make_uint4(pkbf(o0, o1), pkbf(o2, o3), pkbf(o4, o5), pkbf(o6, o7));
}

// ---------------- MFMA fc + log_softmax: 16 rows/block, 1 wave, K=384, N pad 48 ----------------
__global__ __launch_bounds__(64) void fc_logsoftmax(
    const unsigned* __restrict__ oxu, const unsigned* __restrict__ oyu,
    const unsigned* __restrict__ xbf,
    const unsigned* __restrict__ wbf, const float* __restrict__ fcb,
    float* __restrict__ out, int n)
{
    __shared__ unsigned xl[16 * 192];   // 12 KB: 16 rows x 48 uint4-slots
    const int t = threadIdx.x;
    const int row0 = blockIdx.x * 16;

#pragma unroll
    for (int i = 0; i < 12; ++i) {
        int q = t + i * 64;
        int r = q / 48, sl = q % 48;
        int gr = row0 + r; if (gr >= n) gr = n - 1;
        const unsigned* S = (sl < 16) ? oxu : ((sl < 32) ? oyu : xbf);
        int slo = (sl < 16) ? sl : ((sl < 32) ? sl - 16 : sl - 32);
        uint4 v = ((const uint4*)S)[(size_t)gr * 16 + slo];
        int dsl = sl ^ (r & 7);
        *(uint4*)&xl[r * 192 + dsl * 4] = v;
    }
    __syncthreads();

    const int c = t & 15, q4 = t >> 4;   // single wave: rows 0..15
    f32x4 acc[3];
#pragma unroll
    for (int nt = 0; nt < 3; ++nt) acc[nt] = (f32x4){0.f, 0.f, 0.f, 0.f};

#pragma unroll
    for (int ks = 0; ks < 12; ++ks) {
        int gslot = ks * 4 + q4;
        int slot = gslot ^ (c & 7);
        s16x8 af = *(const s16x8*)&xl[c * 192 + slot * 4];
#pragma unroll
        for (int nt = 0; nt < 3; ++nt) {
            int wr = nt * 16 + c;
            s16x8 bfr = *(const s16x8*)&wbf[(size_t)wr * 192 + gslot * 4];
            acc[nt] = __builtin_amdgcn_mfma_f32_16x16x32_bf16(af, bfr, acc[nt], 0, 0, 0);
        }
    }

    float vb[3];
#pragma unroll
    for (int nt = 0; nt < 3; ++nt) {
        int col = nt * 16 + c;
        vb[nt] = (col < 40) ? fcb[col] : 0.f;
    }
    const int grow0 = row0 + q4 * 4;
#pragma unroll
    for (int j = 0; j < 4; ++j) {
        float v0 = acc[0][j] + vb[0];
        float v1 = acc[1][j] + vb[1];
        float v2 = (c < 8) ? (acc[2][j] + vb[2]) : -INFINITY;
        float m0 = fmaxf(fmaxf(v0, v1), v2);
#pragma unroll
        for (int o = 1; o < 16; o <<= 1) m0 = fmaxf(m0, __shfl_xor(m0, o));
        float s0 = __expf(v0 - m0) + __expf(v1 - m0) + ((c < 8) ? __expf(v2 - m0) : 0.f);
#pragma unroll
        for (int o = 1; o < 16; o <<= 1) s0 += __shfl_xor(s0, o);
        float lse = m0 + logf(s0);
        int grow = grow0 + j;
        if (grow < n) {
            out[(size_t)grow * 40 + c] = v0 - lse;
            out[(size_t)grow * 40 + 16 + c] = v1 - lse;
            if (c < 8) out[(size_t)grow * 40 + 32 + c] = v2 - lse;
        }
    }
}

extern "C" void kernel_launch(void* const* d_in, const int* in_sizes, int n_in,
                              void* d_out, int out_size, void* d_ws, size_t ws_size,
                              hipStream_t stream)
{
    const float* x    = (const float*)d_in[0];
    const float* y    = (const float*)d_in[1];
    const int*   eix  = (const int*)d_in[2];
    const int*   eiy  = (const int*)d_in[3];
    const float* a1iw = (const float*)d_in[4];
    const float* a1ib = (const float*)d_in[5];
    const float* a1ow = (const float*)d_in[6];
    const float* a1ob = (const float*)d_in[7];
    const float* a2iw = (const float*)d_in[8];
    const float* a2ib = (const float*)d_in[9];
    const float* a2ow = (const float*)d_in[10];
    const float* a2ob = (const float*)d_in[11];
    const float* g1w  = (const float*)d_in[12];
    const float* g1as = (const float*)d_in[13];
    const float* g1ad = (const float*)d_in[14];
    const float* g1b  = (const float*)d_in[15];
    const float* g2xw = (const float*)d_in[16];
    const float* g2xas= (const float*)d_in[17];
    const float* g2xad= (const float*)d_in[18];
    const float* g2xb = (const float*)d_in[19];
    const float* g2yw = (const float*)d_in[20];
    const float* g2yas= (const float*)d_in[21];
    const float* g2yad= (const float*)d_in[22];
    const float* g2yb = (const float*)d_in[23];
    const float* fcw  = (const float*)d_in[24];
    const float* fcb  = (const float*)d_in[25];
    float* outp = (float*)d_out;

    const int N = in_sizes[0] / 128;
    const int E = in_sizes[2] / 2;
    (void)n_in; (void)out_size; (void)ws_size;

    size_t NU = (size_t)N * 64;              // uints per packed node buffer
    unsigned* u0 = (unsigned*)d_ws;          // xa -> r1x -> ox  (bf16 packed)
    unsigned* u1 = u0 + NU;                  // hx -> h2x        (fp8, N*32 used)
    unsigned* u2 = u1 + NU;                  // ya -> r1y -> oy  (bf16 packed)
    unsigned* u3 = u2 + NU;                  // hy -> h2y        (fp8, N*32 used)
    unsigned* u4 = u3 + NU;                  // x residual, bf16 packed
    float* ssx = (float*)(u4 + NU);
    float* sdx = ssx + N;
    float* ssy = sdx + N;
    float* sdy = ssy + N;
    float* cw1 = sdy + N;
    float* cb1 = cw1 + 128 * 128;
    float* cw2 = cb1 + 128;
    float* cb2 = cw2 + 128 * 128;
    const int Npad = (N + 4) & ~3;
    int* offx = (int*)(cb2 + 128);           // N+1
    int* offy = offx + Npad;
    int* bbx  = offy + Npad;                 // nbk+1 (<=65), pad 128
    int* bby  = bbx + 128;
    int* bcx  = bby + 128;                   // 64
    int* bcy  = bcx + 64;
    int* curx = bcy + 64;                    // 64
    int* cury = curx + 64;
    unsigned* pkx = (unsigned*)(cury + 64);  // E+N packed entries
    unsigned* pky = pkx + (E + N);
    unsigned short* csx = (unsigned short*)(pky + (E + N));   // E+N ushort
    unsigned short* csy = csx + (((E + N) + 1) & ~1);
    unsigned* wbf = (unsigned*)(csy + (((E + N) + 1) & ~1));  // 48*192 uints
    unsigned* wpk = wbf + 48 * 192;          // 5*128*64 uints (bf16 weights)

    const int ET = E + N;
    const int NBK = (N + RPB - 1) >> LOG_R;  // <= 64 required (N <= 65536)
    const int gG = (N + 63) / 64;            // 64 rows per 4-wave block
    const int gA = (N + 15) / 16;
    const int nAB = (ET + EPB - 1) / EPB;

    mha_combine2<<<128, 256, 0, stream>>>(a1iw, a1ib, a1ow, a1ob,
                                          a2iw, a2ib, a2ow, a2ob,
                                          cw1, cb1, cw2, cb2);
    wpack5<<<160, 256, 0, stream>>>(cw1, cw2, g1w, g2xw, g2yw, wpk);
    fcw_prep<<<(48 * 192 + 255) / 256, 256, 0, stream>>>(fcw, wbf);

    // ---- build both CSRs (two-level bucket sort) ----
    hipMemsetAsync(bcx, 0, 128 * sizeof(int), stream);   // bcx+bcy
    hist_bucket2<<<256, 256, 0, stream>>>(eix, eiy, E, N, bcx, bcy, 128);
    bscan<<<1, 128, 0, stream>>>(bcx, bcy, NBK, bbx, bby, curx, cury, offx + N, offy + N);
    bucket_pass<<<2 * nAB, 256, 0, stream>>>(eix, eiy, E, N, curx, cury, pkx, pky, nAB);
    fine_sort<<<2 * NBK, 256, 0, stream>>>(pkx, pky, bbx, bby, offx, offy, csx, csy, N, NBK);

    // ---- MHA projection (both) -> bf16 packed; also saves x as bf16 (u4) ----
    gemm_mfma2<false, false><<<2 * gG, 256, 0, stream>>>(
        x, y, wpk, wpk + 8192, cb1, cb2,
        nullptr, nullptr, nullptr, nullptr,
        u0, u2,
        nullptr, nullptr, nullptr, nullptr,
        u4, nullptr, N, gG);

    // ---- GAT layer 1 (both): GEMM -> fp8 h, aggregate -> bf16 packed ----
    gemm_mfma2<true, true><<<2 * gG, 256, 0, stream>>>(
        u0, u2, wpk + 2 * 8192, wpk + 2 * 8192, nullptr, nullptr,
        g1as, g1ad, g1as, g1ad,
        u1, u3,
        ssx, sdx, ssy, sdy,
        nullptr, nullptr, N, gG);
    gat_aggregate2<<<2 * gA, 256, 0, stream>>>(
        offx, csx, ssx, sdx, (const unsigned char*)u1, g1b, u0,
        offy, csy, ssy, sdy, (const unsigned char*)u3, g1b, u2,
        N, 1, gA);

    // ---- GAT layer 2 (both) ----
    gemm_mfma2<true, true><<<2 * gG, 256, 0, stream>>>(
        u0, u2, wpk + 3 * 8192, wpk + 4 * 8192, nullptr, nullptr,
        g2xas, g2xad, g2yas, g2yad,
        u1, u3,
        ssx, sdx, ssy, sdy,
        nullptr, nullptr, N, gG);
    gat_aggregate2<<<2 * gA, 256, 0, stream>>>(
        offx, csx, ssx, sdx, (const unsigned char*)u1, g2xb, u0,
        offy, csy, ssy, sdy, (const unsigned char*)u3, g2yb, u2,
        N, 0, gA);

    // ---- fusion fc + log_softmax (MFMA, 16 rows/block) ----
    fc_logsoftmax<<<(N + 15) / 16, 64, 0, stream>>>(u0, u2, u4, wbf, fcb, outp, N);
}

// Round 21
// 222.610 us; speedup vs baseline: 1.2804x; 1.2804x over previous
//
#include <hip/hip_runtime.h>
#include <hip/hip_bf16.h>
#include <hip/hip_fp16.h>

#define NEG_SLOPE 0.2f
#define LOG_R 10
#define RPB (1 << LOG_R)      // dsts per coarse bucket
#define EPB 4096              // edges per bucket_pass block
#define CAPB 24576            // fine_sort LDS staging entries

typedef __attribute__((ext_vector_type(4))) float f32x4;
typedef __attribute__((ext_vector_type(2))) float f32x2;
typedef __attribute__((ext_vector_type(8))) short s16x8;

static __device__ __forceinline__ unsigned pkbf(float a, float b) {
    unsigned ua = __float_as_uint(a);
    ua = (ua + 0x7FFFu + ((ua >> 16) & 1u)) >> 16;
    unsigned ub = __float_as_uint(b);
    ub = (ub + 0x7FFFu + ((ub >> 16) & 1u)) & 0xFFFF0000u;
    return (ua & 0xFFFFu) | ub;
}
static __device__ __forceinline__ unsigned short bf1(float a) {
    unsigned ua = __float_as_uint(a);
    return (unsigned short)((ua + 0x7FFFu + ((ua >> 16) & 1u)) >> 16);
}
static __device__ __forceinline__ float bflo(unsigned u) { return __uint_as_float(u << 16); }
static __device__ __forceinline__ float bfhi(unsigned u) { return __uint_as_float(u & 0xFFFF0000u); }

// both MHA weight-combines in one kernel
__global__ __launch_bounds__(256) void mha_combine2(
    const float* __restrict__ iw1, const float* __restrict__ ib1,
    const float* __restrict__ ow1, const float* __restrict__ ob1,
    const float* __restrict__ iw2, const float* __restrict__ ib2,
    const float* __restrict__ ow2, const float* __restrict__ ob2,
    float* __restrict__ cw1, float* __restrict__ cb1,
    float* __restrict__ cw2, float* __restrict__ cb2)
{
    int idx = blockIdx.x * blockDim.x + threadIdx.x;
    int set = idx >> 14;
    int local = idx & 16383;
    int o = local >> 7, i = local & 127;
    const float* in_w  = set ? iw2 : iw1;
    const float* in_b  = set ? ib2 : ib1;
    const float* out_w = set ? ow2 : ow1;
    const float* out_b = set ? ob2 : ob1;
    float* combW = set ? cw2 : cw1;
    float* combb = set ? cb2 : cb1;
    float a = 0.f;
    for (int k = 0; k < 128; ++k)
        a = fmaf(out_w[o * 128 + k], in_w[(256 + k) * 128 + i], a);
    combW[local] = a;
    if (i == 0) {
        float b = out_b[o];
        for (int k = 0; k < 128; ++k)
            b = fmaf(out_w[o * 128 + k], in_b[256 + k], b);
        combb[o] = b;
    }
}

// fold MHA into GAT1: W1 = g1w @ cw, b1 = g1w . cb  (x and y sets)
__global__ __launch_bounds__(256) void wcomb2(
    const float* __restrict__ g1w,
    const float* __restrict__ cw1, const float* __restrict__ cb1,
    const float* __restrict__ cw2, const float* __restrict__ cb2,
    float* __restrict__ w1x, float* __restrict__ b1x,
    float* __restrict__ w1y, float* __restrict__ b1y)
{
    int idx = blockIdx.x * blockDim.x + threadIdx.x;
    if (idx >= 2 * 16384) return;
    int set = idx >> 14;
    int local = idx & 16383;
    int o = local >> 7, i = local & 127;
    const float* cw = set ? cw2 : cw1;
    const float* cb = set ? cb2 : cb1;
    float* wo = set ? w1y : w1x;
    float* bo = set ? b1y : b1x;
    float a = 0.f;
    for (int k = 0; k < 128; ++k)
        a = fmaf(g1w[o * 128 + k], cw[k * 128 + i], a);
    wo[local] = a;
    if (i == 0) {
        float b = 0.f;
        for (int k = 0; k < 128; ++k)
            b = fmaf(g1w[o * 128 + k], cb[k], b);
        bo[o] = b;
    }
}

// fc weight prep: f32 [40][384] -> packed bf16 [48][384] (rows 40..47 zero)
__global__ __launch_bounds__(256) void fcw_prep(
    const float* __restrict__ fcw, unsigned* __restrict__ wbf)
{
    int i = blockIdx.x * 256 + threadIdx.x;
    if (i >= 48 * 192) return;
    unsigned v = 0;
    if (i < 40 * 192) {
        float2 f = ((const float2*)fcw)[i];
        v = pkbf(f.x, f.y);
    }
    wbf[i] = v;
}

// Fused two-graph MFMA GEMM (best-measured R16 structure): 64 rows/block,
// 4 waves; A 16 KB + W 32 KB LDS. HFP8: store h as fp8 e4m3; else bf16.
// ao*: optional packed-bf16 copy of the staged A input (saves x->bf16 for fc).
template<bool ABF, bool HFP8>
__global__ __launch_bounds__(256) void gemm_mfma2(
    const void* __restrict__ A0, const void* __restrict__ A1,
    const float* __restrict__ W0, const float* __restrict__ W1,
    const float* __restrict__ bias0, const float* __restrict__ bias1,
    const float* __restrict__ as0, const float* __restrict__ ad0,
    const float* __restrict__ as1, const float* __restrict__ ad1,
    void* __restrict__ h0, void* __restrict__ h1,
    float* __restrict__ ss0, float* __restrict__ sd0,
    float* __restrict__ ss1, float* __restrict__ sd1,
    unsigned* __restrict__ ao0, unsigned* __restrict__ ao1,
    int n, int half)
{
    __shared__ unsigned xl[64 * 64];    // A tile bf16 pairs, 16 KB
    __shared__ unsigned wl[128 * 64];   // W bf16 pairs, 32 KB

    int b = blockIdx.x;
    const void* Ain; const float *W, *bias, *asrc, *adst;
    void* hbs; float *ssrc, *sdst; unsigned* aout;
    if (b < half) { Ain = A0; W = W0; bias = bias0; asrc = as0; adst = ad0; hbs = h0; ssrc = ss0; sdst = sd0; aout = ao0; }
    else { b -= half; Ain = A1; W = W1; bias = bias1; asrc = as1; adst = ad1; hbs = h1; ssrc = ss1; sdst = sd1; aout = ao1; }

    const int t = threadIdx.x;
    const int row0 = b * 64;

#pragma unroll
    for (int i = 0; i < 4; ++i) {
        int q = t + i * 256;
        int r = q >> 4, sl = q & 15;
        int gr = row0 + r; if (gr >= n) gr = n - 1;
        unsigned p0, p1, p2, p3;
        if (ABF) {
            uint4 v = ((const uint4*)Ain)[(size_t)gr * 16 + sl];
            p0 = v.x; p1 = v.y; p2 = v.z; p3 = v.w;
        } else {
            float4 a = ((const float4*)Ain)[(size_t)gr * 32 + sl * 2];
            float4 bb = ((const float4*)Ain)[(size_t)gr * 32 + sl * 2 + 1];
            p0 = pkbf(a.x, a.y); p1 = pkbf(a.z, a.w);
            p2 = pkbf(bb.x, bb.y); p3 = pkbf(bb.z, bb.w);
            if (aout) ((uint4*)aout)[(size_t)gr * 16 + sl] = make_uint4(p0, p1, p2, p3);
        }
        int dsl = sl ^ (r & 7);
        *(uint4*)&xl[r * 64 + dsl * 4] = make_uint4(p0, p1, p2, p3);
    }
#pragma unroll
    for (int i = 0; i < 8; ++i) {
        int q = t + i * 256;
        int r = q >> 4, sl = q & 15;
        float4 a = ((const float4*)W)[(size_t)r * 32 + sl * 2];
        float4 bb = ((const float4*)W)[(size_t)r * 32 + sl * 2 + 1];
        int dsl = sl ^ (r & 7);
        *(uint4*)&wl[r * 64 + dsl * 4] = make_uint4(
            pkbf(a.x, a.y), pkbf(a.z, a.w), pkbf(bb.x, bb.y), pkbf(bb.z, bb.w));
    }
    __syncthreads();

    const int l = t & 63, w = t >> 6;
    const int c = l & 15, q4 = l >> 4;
    const int rloc = w * 16 + c;
    f32x4 acc[8];
#pragma unroll
    for (int nt = 0; nt < 8; ++nt) acc[nt] = (f32x4){0.f, 0.f, 0.f, 0.f};

#pragma unroll
    for (int s = 0; s < 4; ++s) {
        int slot = (s * 4 + q4) ^ (c & 7);
        s16x8 af = *(const s16x8*)&xl[rloc * 64 + slot * 4];
#pragma unroll
        for (int nt = 0; nt < 8; ++nt) {
            int wr = nt * 16 + c;
            s16x8 bfr = *(const s16x8*)&wl[wr * 64 + slot * 4];
            acc[nt] = __builtin_amdgcn_mfma_f32_16x16x32_bf16(af, bfr, acc[nt], 0, 0, 0);
        }
    }

    float bv[8], as8[8], ad8[8];
#pragma unroll
    for (int nt = 0; nt < 8; ++nt) {
        bv[nt]  = bias ? bias[nt * 16 + c] : 0.f;
        as8[nt] = asrc ? asrc[nt * 16 + c] : 0.f;
        ad8[nt] = asrc ? adst[nt * 16 + c] : 0.f;
    }
    float ps[4] = {0.f, 0.f, 0.f, 0.f}, pd[4] = {0.f, 0.f, 0.f, 0.f};
    const int grow0 = row0 + w * 16 + q4 * 4;
#pragma unroll
    for (int nt = 0; nt < 8; ++nt) {
#pragma unroll
        for (int j = 0; j < 4; ++j) {
            float val = acc[nt][j] + bv[nt];
            if (grow0 + j < n) {
                if (HFP8) {
                    unsigned b8 = (unsigned)__builtin_amdgcn_cvt_pk_fp8_f32(val, val, 0, false);
                    ((unsigned char*)hbs)[(size_t)(grow0 + j) * 128 + nt * 16 + c] = (unsigned char)b8;
                } else {
                    ((unsigned short*)hbs)[(size_t)(grow0 + j) * 128 + nt * 16 + c] = bf1(val);
                }
            }
            ps[j] = fmaf(val, as8[nt], ps[j]);
            pd[j] = fmaf(val, ad8[nt], pd[j]);
        }
    }
    if (asrc) {
#pragma unroll
        for (int j = 0; j < 4; ++j) {
            float a = ps[j], bb = pd[j];
#pragma unroll
            for (int o = 1; o < 16; o <<= 1) {
                a += __shfl_xor(a, o);
                bb += __shfl_xor(bb, o);
            }
            if (c == 0 && grow0 + j < n) { ssrc[grow0 + j] = a; sdst[grow0 + j] = bb; }
        }
    }
}

// ---------------- CSR build: two-level bucket sort ----------------

__global__ __launch_bounds__(256) void hist_bucket2(
    const int* __restrict__ eix, const int* __restrict__ eiy, int E, int n,
    int* __restrict__ bcx, int* __restrict__ bcy, int half)
{
    __shared__ int lh[64];
    int gb = blockIdx.x;
    const int* ei = eix; int* bc = bcx;
    if (gb >= half) { gb -= half; ei = eiy; bc = bcy; }
    int t = threadIdx.x;
    int ET = E + n;
    int nbk = (n + RPB - 1) >> LOG_R;
    for (int i = t; i < nbk; i += 256) lh[i] = 0;
    __syncthreads();
    for (int e = gb * 256 + t; e < ET; e += half * 256) {
        int d = (e < E) ? ei[E + e] : (e - E);
        atomicAdd(&lh[d >> LOG_R], 1);
    }
    __syncthreads();
    if (t < nbk) atomicAdd(&bc[t], lh[t]);
}

__global__ void bscan(
    const int* __restrict__ bcx, const int* __restrict__ bcy, int nbk,
    int* __restrict__ bbx, int* __restrict__ bby,
    int* __restrict__ curx, int* __restrict__ cury,
    int* __restrict__ offx_n, int* __restrict__ offy_n)
{
    int w = threadIdx.x >> 6, lane = threadIdx.x & 63;
    if (w > 1) return;
    const int* bc = w ? bcy : bcx;
    int* bb  = w ? bby : bbx;
    int* cur = w ? cury : curx;
    int* offn = w ? offy_n : offx_n;
    int c = (lane < nbk) ? bc[lane] : 0;
    int v = c;
#pragma unroll
    for (int o = 1; o < 64; o <<= 1) {
        int u = __shfl_up(v, o);
        if (lane >= o) v += u;
    }
    int excl = v - c;
    if (lane < nbk) { bb[lane] = excl; cur[lane] = excl; }
    if (lane == 63) { bb[nbk] = v; *offn = v; }
}

// pass A: bucket edges by dst>>LOG_R; per-block LDS sort + contiguous run flush.
__global__ __launch_bounds__(256) void bucket_pass(
    const int* __restrict__ eix, const int* __restrict__ eiy, int E, int n,
    int* __restrict__ curx, int* __restrict__ cury,
    unsigned* __restrict__ pkx, unsigned* __restrict__ pky, int half)
{
    __shared__ int lhist[64], lbase[64], gbase[64], lpos[64];
    __shared__ unsigned stg[EPB];
    __shared__ int gidx[EPB];
    int gb = blockIdx.x;
    const int* ei = eix; int* bcur = curx; unsigned* pk = pkx;
    if (gb >= half) { gb -= half; ei = eiy; bcur = cury; pk = pky; }
    const int t = threadIdx.x;
    const int ET = E + n;
    const int nbk = (n + RPB - 1) >> LOG_R;   // must be <= 64
    const int base = gb * EPB;

    for (int i = t; i < nbk; i += 256) lhist[i] = 0;
    __syncthreads();

    unsigned mypk[16];
    int myb[16];
#pragma unroll
    for (int k = 0; k < 16; ++k) {
        int e = base + k * 256 + t;
        if (e < ET) {
            int s, d;
            if (e < E) { s = ei[e]; d = ei[E + e]; }
            else       { s = e - E; d = e - E; }
            myb[k] = d >> LOG_R;
            mypk[k] = ((unsigned)s << LOG_R) | (unsigned)(d & (RPB - 1));
            atomicAdd(&lhist[myb[k]], 1);
        } else myb[k] = -1;
    }
    __syncthreads();

    if (t < 64) {
        int c = (t < nbk) ? lhist[t] : 0;
        int v = c;
#pragma unroll
        for (int o = 1; o < 64; o <<= 1) {
            int u = __shfl_up(v, o);
            if (t >= o) v += u;
        }
        int excl = v - c;
        if (t < nbk) {
            lbase[t] = excl;
            lpos[t] = excl;
            gbase[t] = c ? atomicAdd(&bcur[t], c) : 0;
        }
    }
    __syncthreads();

#pragma unroll
    for (int k = 0; k < 16; ++k) {
        if (myb[k] >= 0) {
            int p = atomicAdd(&lpos[myb[k]], 1);
            stg[p] = mypk[k];
            gidx[p] = gbase[myb[k]] + (p - lbase[myb[k]]);
        }
    }
    __syncthreads();

    int tot = lbase[nbk - 1] + lhist[nbk - 1];
    for (int i = t; i < tot; i += 256) pk[gidx[i]] = stg[i];
}

// pass B: one block per bucket; per-dst hist + scan (produces off[]), then
// in-LDS scatter and coalesced ushort writeback.
__global__ __launch_bounds__(256) void fine_sort(
    const unsigned* __restrict__ pkx, const unsigned* __restrict__ pky,
    const int* __restrict__ bbx, const int* __restrict__ bby,
    int* __restrict__ offx, int* __restrict__ offy,
    unsigned short* __restrict__ csx, unsigned short* __restrict__ csy,
    int n, int half)
{
    __shared__ int cur[RPB];
    __shared__ int ws[256];
    __shared__ unsigned short outs[CAPB];
    int gb = blockIdx.x;
    const unsigned* pk; const int* bb; int* off; unsigned short* cs;
    if (gb < half) { pk = pkx; bb = bbx; off = offx; cs = csx; }
    else { gb -= half; pk = pky; bb = bby; off = offy; cs = csy; }
    const int t = threadIdx.x;
    const int d0 = gb << LOG_R;
    const int nd = min(RPB, n - d0);
    const int base = bb[gb];
    const int sz = bb[gb + 1] - base;

    for (int i = t; i < RPB; i += 256) cur[i] = 0;
    __syncthreads();
    for (int i = t; i < sz; i += 256)
        atomicAdd(&cur[pk[base + i] & (RPB - 1)], 1);
    __syncthreads();

    int c0 = cur[t * 4], c1 = cur[t * 4 + 1], c2 = cur[t * 4 + 2], c3 = cur[t * 4 + 3];
    int s = c0 + c1 + c2 + c3;
    ws[t] = s; __syncthreads();
    for (int o = 1; o < 256; o <<= 1) {
        int a = (t >= o) ? ws[t - o] : 0;
        __syncthreads();
        ws[t] += a;
        __syncthreads();
    }
    int ex = ws[t] - s;
    int e0 = ex, e1 = ex + c0, e2 = e1 + c1, e3 = e2 + c2;
    cur[t * 4] = e0; cur[t * 4 + 1] = e1; cur[t * 4 + 2] = e2; cur[t * 4 + 3] = e3;
    int i0 = t * 4;
    if (i0     < nd) off[d0 + i0]     = base + e0;
    if (i0 + 1 < nd) off[d0 + i0 + 1] = base + e1;
    if (i0 + 2 < nd) off[d0 + i0 + 2] = base + e2;
    if (i0 + 3 < nd) off[d0 + i0 + 3] = base + e3;
    __syncthreads();

    if (sz <= CAPB) {
        for (int i = t; i < sz; i += 256) {
            unsigned p = pk[base + i];
            int pos = atomicAdd(&cur[p & (RPB - 1)], 1);
            outs[pos] = (unsigned short)(p >> LOG_R);
        }
        __syncthreads();
        for (int i = t; i < sz; i += 256) cs[base + i] = outs[i];
    } else {
        for (int i = t; i < sz; i += 256) {
            unsigned p = pk[base + i];
            int pos = atomicAdd(&cur[p & (RPB - 1)], 1);
            cs[base + pos] = (unsigned short)(p >> LOG_R);
        }
    }
}

// ---------------- fused two-graph GAT aggregation ----------------
// h stored as fp8 e4m3 (128 B/row = 16 lanes x 8 B). FOUR nodes per wave;
// stg padded to 34 entries/node so the 4 quarter-broadcasts hit distinct banks.
__global__ __launch_bounds__(256) void gat_aggregate2(
    const int* __restrict__ off0, const unsigned short* __restrict__ cs0,
    const float* __restrict__ ss0, const float* __restrict__ sd0,
    const unsigned char* __restrict__ hb0, const float* __restrict__ bias0,
    unsigned* __restrict__ out0,
    const int* __restrict__ off1, const unsigned short* __restrict__ cs1,
    const float* __restrict__ ss1, const float* __restrict__ sd1,
    const unsigned char* __restrict__ hb1, const float* __restrict__ bias1,
    unsigned* __restrict__ out1,
    int n, int relu, int half)
{
    __shared__ uint2 stg[4][4][34];
    int b = blockIdx.x;
    const int *off; const unsigned short *csrc; const float *ssrc, *sdst, *bias;
    const unsigned char* hb; unsigned* outu;
    if (b < half) { off = off0; csrc = cs0; ssrc = ss0; sdst = sd0; hb = hb0; bias = bias0; outu = out0; }
    else { b -= half; off = off1; csrc = cs1; ssrc = ss1; sdst = sd1; hb = hb1; bias = bias1; outu = out1; }

    const int w = threadIdx.x >> 6;          // wave in block
    const int lane = threadIdx.x & 63;
    const int qw = lane >> 4;                // quarter-wave = node slot
    const int l16 = lane & 15;
    int node = b * 16 + w * 4 + qw;
    const int valid = node < n;
    if (node >= n) node = n - 1;             // clamp (writes guarded)
    const int p0 = off[node], p1 = off[node + 1];
    const int deg = p1 - p0;
    const float sd = sdst[node];

    // pass A: each lane handles neighbors l16 and l16+16 (exp directly, no max)
    unsigned s0 = 0, s1 = 0;
    float e0 = 0.f, e1 = 0.f;
    if (l16 < deg) {
        s0 = csrc[p0 + l16];
        float v = ssrc[s0] + sd;
        v = (v > 0.f) ? v : NEG_SLOPE * v;
        e0 = __expf(v);
    }
    if (l16 + 16 < deg) {
        s1 = csrc[p0 + 16 + l16];
        float v = ssrc[s1] + sd;
        v = (v > 0.f) ? v : NEG_SLOPE * v;
        e1 = __expf(v);
    }
    float ssum = e0 + e1;
    for (int p = p0 + 32 + l16; p < p1; p += 16) {    // rare deg>32 overflow
        int s = csrc[p];
        float v = ssrc[s] + sd;
        v = (v > 0.f) ? v : NEG_SLOPE * v;
        ssum += __expf(v);
    }
#pragma unroll
    for (int o = 8; o; o >>= 1) ssum += __shfl_xor(ssum, o);

    // stage (src<<7, e) for 32 slots per node; padding entries have e=0
    stg[w][qw][l16]      = make_uint2(s0 << 7, __float_as_uint(e0));
    stg[w][qw][l16 + 16] = make_uint2(s1 << 7, __float_as_uint(e1));

    const unsigned clo = (unsigned)l16 * 8u;          // byte offset: 8 fp8 cols
    float a0 = 0.f, a1 = 0.f, a2 = 0.f, a3 = 0.f;
    float a4 = 0.f, a5 = 0.f, a6 = 0.f, a7 = 0.f;

    int jcap = deg < 32 ? deg : 32;
    int j = 0;
    for (; j + 8 <= jcap; j += 8) {
        uint2 q[8];
#pragma unroll
        for (int k = 0; k < 8; ++k) q[k] = stg[w][qw][j + k];   // broadcast per quarter
        uint2 u[8];
#pragma unroll
        for (int k = 0; k < 8; ++k)
            u[k] = *(const uint2*)(hb + (size_t)(q[k].x | clo));
#pragma unroll
        for (int k = 0; k < 8; ++k) {
            float e = __uint_as_float(q[k].y);
            f32x2 f0 = __builtin_amdgcn_cvt_pk_f32_fp8((int)u[k].x, false);
            f32x2 f1 = __builtin_amdgcn_cvt_pk_f32_fp8((int)u[k].x, true);
            f32x2 f2 = __builtin_amdgcn_cvt_pk_f32_fp8((int)u[k].y, false);
            f32x2 f3 = __builtin_amdgcn_cvt_pk_f32_fp8((int)u[k].y, true);
            a0 = fmaf(e, f0[0], a0); a1 = fmaf(e, f0[1], a1);
            a2 = fmaf(e, f1[0], a2); a3 = fmaf(e, f1[1], a3);
            a4 = fmaf(e, f2[0], a4); a5 = fmaf(e, f2[1], a5);
            a6 = fmaf(e, f3[0], a6); a7 = fmaf(e, f3[1], a7);
        }
    }
    for (; j < jcap; ++j) {
        uint2 q = stg[w][qw][j];
        uint2 u = *(const uint2*)(hb + (size_t)(q.x | clo));
        float e = __uint_as_float(q.y);
        f32x2 f0 = __builtin_amdgcn_cvt_pk_f32_fp8((int)u.x, false);
        f32x2 f1 = __builtin_amdgcn_cvt_pk_f32_fp8((int)u.x, true);
        f32x2 f2 = __builtin_amdgcn_cvt_pk_f32_fp8((int)u.y, false);
        f32x2 f3 = __builtin_amdgcn_cvt_pk_f32_fp8((int)u.y, true);
        a0 = fmaf(e, f0[0], a0); a1 = fmaf(e, f0[1], a1);
        a2 = fmaf(e, f1[0], a2); a3 = fmaf(e, f1[1], a3);
        a4 = fmaf(e, f2[0], a4); a5 = fmaf(e, f2[1], a5);
        a6 = fmaf(e, f3[0], a6); a7 = fmaf(e, f3[1], a7);
    }
    for (int p = p0 + 32; p < p1; ++p) {              // rare deg>32 overflow
        int s = csrc[p];
        float v = ssrc[s] + sd;
        v = (v > 0.f) ? v : NEG_SLOPE * v;
        float e = __expf(v);
        uint2 u = *(const uint2*)(hb + (((size_t)s << 7) | clo));
        f32x2 f0 = __builtin_amdgcn_cvt_pk_f32_fp8((int)u.x, false);
        f32x2 f1 = __builtin_amdgcn_cvt_pk_f32_fp8((int)u.x, true);
        f32x2 f2 = __builtin_amdgcn_cvt_pk_f32_fp8((int)u.y, false);
        f32x2 f3 = __builtin_amdgcn_cvt_pk_f32_fp8((int)u.y, true);
        a0 = fmaf(e, f0[0], a0); a1 = fmaf(e, f0[1], a1);
        a2 = fmaf(e, f1[0], a2); a3 = fmaf(e, f1[1], a3);
        a4 = fmaf(e, f2[0], a4); a5 = fmaf(e, f2[1], a5);
        a6 = fmaf(e, f3[0], a6); a7 = fmaf(e, f3[1], a7);
    }

    float inv = 1.f / (ssum + 1e-16f);
    float4 bva = ((const float4*)bias)[l16 * 2];
    float4 bvb = ((const float4*)bias)[l16 * 2 + 1];
    float o0 = fmaf(a0, inv, bva.x);
    float o1 = fmaf(a1, inv, bva.y);
    float o2 = fmaf(a2, inv, bva.z);
    float o3 = fmaf(a3, inv, bva.w);
    float o4 = fmaf(a4, inv, bvb.x);
    float o5 = fmaf(a5, inv, bvb.y);
    float o6 = fmaf(a6, inv, bvb.z);
    float o7 = fmaf(a7, inv, bvb.w);
    if (relu) {
        o0 = fmaxf(o0, 0.f); o1 = fmaxf(o1, 0.f);
        o2 = fmaxf(o2, 0.f); o3 = fmaxf(o3, 0.f);
        o4 = fmaxf(o4, 0.f); o5 = fmaxf(o5, 0.f);
        o6 = fmaxf(o6, 0.f); o7 = fmaxf(o7, 0.f);
    }
    if (valid)
        ((uint4*)(outu + (size_t)node * 64))[l16] =
            make_uint4(pkbf(o0, o1), pkbf(o2, o3), pkbf(o4, o5), pkbf(o6, o7));
}

// ---------------- MFMA fc + log_softmax: 16 rows/block, 1 wave, K=384, N pad 48 ----------------
__global__ __launch_bounds__(64) void fc_logsoftmax(
    const unsigned* __restrict__ oxu, const unsigned* __restrict__ oyu,
    const unsigned* __restrict__ xbf,
    const unsigned* __restrict__ wbf, const float* __restrict__ fcb,
    float* __restrict__ out, int n)
{
    __shared__ unsigned xl[16 * 192];   // 12 KB: 16 rows x 48 uint4-slots
    const int t = threadIdx.x;
    const int row0 = blockIdx.x * 16;

#pragma unroll
    for (int i = 0; i < 12; ++i) {
        int q = t + i * 64;
        int r = q / 48, sl = q % 48;
        int gr = row0 + r; if (gr >= n) gr = n - 1;
        const unsigned* S = (sl < 16) ? oxu : ((sl < 32) ? oyu : xbf);
        int slo = (sl < 16) ? sl : ((sl < 32) ? sl - 16 : sl - 32);
        uint4 v = ((const uint4*)S)[(size_t)gr * 16 + slo];
        int dsl = sl ^ (r & 7);
        *(uint4*)&xl[r * 192 + dsl * 4] = v;
    }
    __syncthreads();

    const int c = t & 15, q4 = t >> 4;   // single wave: rows 0..15
    f32x4 acc[3];
#pragma unroll
    for (int nt = 0; nt < 3; ++nt) acc[nt] = (f32x4){0.f, 0.f, 0.f, 0.f};

#pragma unroll
    for (int ks = 0; ks < 12; ++ks) {
        int gslot = ks * 4 + q4;
        int slot = gslot ^ (c & 7);
        s16x8 af = *(const s16x8*)&xl[c * 192 + slot * 4];
#pragma unroll
        for (int nt = 0; nt < 3; ++nt) {
            int wr = nt * 16 + c;
            s16x8 bfr = *(const s16x8*)&wbf[(size_t)wr * 192 + gslot * 4];
            acc[nt] = __builtin_amdgcn_mfma_f32_16x16x32_bf16(af, bfr, acc[nt], 0, 0, 0);
        }
    }

    float vb[3];
#pragma unroll
    for (int nt = 0; nt < 3; ++nt) {
        int col = nt * 16 + c;
        vb[nt] = (col < 40) ? fcb[col] : 0.f;
    }
    const int grow0 = row0 + q4 * 4;
#pragma unroll
    for (int j = 0; j < 4; ++j) {
        float v0 = acc[0][j] + vb[0];
        float v1 = acc[1][j] + vb[1];
        float v2 = (c < 8) ? (acc[2][j] + vb[2]) : -INFINITY;
        float m0 = fmaxf(fmaxf(v0, v1), v2);
#pragma unroll
        for (int o = 1; o < 16; o <<= 1) m0 = fmaxf(m0, __shfl_xor(m0, o));
        float s0 = __expf(v0 - m0) + __expf(v1 - m0) + ((c < 8) ? __expf(v2 - m0) : 0.f);
#pragma unroll
        for (int o = 1; o < 16; o <<= 1) s0 += __shfl_xor(s0, o);
        float lse = m0 + logf(s0);
        int grow = grow0 + j;
        if (grow < n) {
            out[(size_t)grow * 40 + c] = v0 - lse;
            out[(size_t)grow * 40 + 16 + c] = v1 - lse;
            if (c < 8) out[(size_t)grow * 40 + 32 + c] = v2 - lse;
        }
    }
}

extern "C" void kernel_launch(void* const* d_in, const int* in_sizes, int n_in,
                              void* d_out, int out_size, void* d_ws, size_t ws_size,
                              hipStream_t stream)
{
    const float* x    = (const float*)d_in[0];
    const float* y    = (const float*)d_in[1];
    const int*   eix  = (const int*)d_in[2];
    const int*   eiy  = (const int*)d_in[3];
    const float* a1iw = (const float*)d_in[4];
    const float* a1ib = (const float*)d_in[5];
    const float* a1ow = (const float*)d_in[6];
    const float* a1ob = (const float*)d_in[7];
    const float* a2iw = (const float*)d_in[8];
    const float* a2ib = (const float*)d_in[9];
    const float* a2ow = (const float*)d_in[10];
    const float* a2ob = (const float*)d_in[11];
    const float* g1w  = (const float*)d_in[12];
    const float* g1as = (const float*)d_in[13];
    const float* g1ad = (const float*)d_in[14];
    const float* g1b  = (const float*)d_in[15];
    const float* g2xw = (const float*)d_in[16];
    const float* g2xas= (const float*)d_in[17];
    const float* g2xad= (const float*)d_in[18];
    const float* g2xb = (const float*)d_in[19];
    const float* g2yw = (const float*)d_in[20];
    const float* g2yas= (const float*)d_in[21];
    const float* g2yad= (const float*)d_in[22];
    const float* g2yb = (const float*)d_in[23];
    const float* fcw  = (const float*)d_in[24];
    const float* fcb  = (const float*)d_in[25];
    float* outp = (float*)d_out;

    const int N = in_sizes[0] / 128;
    const int E = in_sizes[2] / 2;
    (void)n_in; (void)out_size; (void)ws_size;

    size_t NU = (size_t)N * 64;              // uints per packed node buffer
    unsigned* u0 = (unsigned*)d_ws;          // r1x -> ox  (bf16 packed)
    unsigned* u1 = u0 + NU;                  // hx (fp8, N*32 used)
    unsigned* u2 = u1 + NU;                  // r1y -> oy  (bf16 packed)
    unsigned* u3 = u2 + NU;                  // hy (fp8, N*32 used)
    unsigned* u4 = u3 + NU;                  // x residual, bf16 packed
    float* ssx = (float*)(u4 + NU);
    float* sdx = ssx + N;
    float* ssy = sdx + N;
    float* sdy = ssy + N;
    float* cw1 = sdy + N;
    float* cb1 = cw1 + 128 * 128;
    float* cw2 = cb1 + 128;
    float* cb2 = cw2 + 128 * 128;
    const int Npad = (N + 4) & ~3;
    int* offx = (int*)(cb2 + 128);           // N+1
    int* offy = offx + Npad;
    int* bbx  = offy + Npad;                 // nbk+1 (<=65), pad 128
    int* bby  = bbx + 128;
    int* bcx  = bby + 128;                   // 64
    int* bcy  = bcx + 64;
    int* curx = bcy + 64;                    // 64
    int* cury = curx + 64;
    unsigned* pkx = (unsigned*)(cury + 64);  // E+N packed entries
    unsigned* pky = pkx + (E + N);
    unsigned short* csx = (unsigned short*)(pky + (E + N));   // E+N ushort
    unsigned short* csy = csx + (((E + N) + 1) & ~1);
    unsigned* wbf = (unsigned*)(csy + (((E + N) + 1) & ~1));  // 48*192 uints
    float* w1cx = (float*)(wbf + 48 * 192);  // 16384 (fused GAT1 weight, x)
    float* b1cx = w1cx + 16384;              // 128
    float* w1cy = b1cx + 128;                // 16384
    float* b1cy = w1cy + 16384;              // 128

    const int ET = E + N;
    const int NBK = (N + RPB - 1) >> LOG_R;  // <= 64 required (N <= 65536)
    const int gG = (N + 63) / 64;
    const int gA = (N + 15) / 16;
    const int nAB = (ET + EPB - 1) / EPB;

    mha_combine2<<<128, 256, 0, stream>>>(a1iw, a1ib, a1ow, a1ob,
                                          a2iw, a2ib, a2ow, a2ob,
                                          cw1, cb1, cw2, cb2);
    wcomb2<<<128, 256, 0, stream>>>(g1w, cw1, cb1, cw2, cb2,
                                    w1cx, b1cx, w1cy, b1cy);
    fcw_prep<<<(48 * 192 + 255) / 256, 256, 0, stream>>>(fcw, wbf);

    // ---- build both CSRs (two-level bucket sort) ----
    hipMemsetAsync(bcx, 0, 128 * sizeof(int), stream);   // bcx+bcy
    hist_bucket2<<<256, 256, 0, stream>>>(eix, eiy, E, N, bcx, bcy, 128);
    bscan<<<1, 128, 0, stream>>>(bcx, bcy, NBK, bbx, bby, curx, cury, offx + N, offy + N);
    bucket_pass<<<2 * nAB, 256, 0, stream>>>(eix, eiy, E, N, curx, cury, pkx, pky, nAB);
    fine_sort<<<2 * NBK, 256, 0, stream>>>(pkx, pky, bbx, bby, offx, offy, csx, csy, N, NBK);

    // ---- fused MHA+GAT1 GEMM (both): x f32 -> fp8 h (+ x saved as bf16) ----
    gemm_mfma2<false, true><<<2 * gG, 256, 0, stream>>>(
        x, y, w1cx, w1cy, b1cx, b1cy,
        g1as, g1ad, g1as, g1ad,
        u1, u3,
        ssx, sdx, ssy, sdy,
        u4, nullptr, N, gG);
    gat_aggregate2<<<2 * gA, 256, 0, stream>>>(
        offx, csx, ssx, sdx, (const unsigned char*)u1, g1b, u0,
        offy, csy, ssy, sdy, (const unsigned char*)u3, g1b, u2,
        N, 1, gA);

    // ---- GAT layer 2 (both) ----
    gemm_mfma2<true, true><<<2 * gG, 256, 0, stream>>>(
        u0, u2, g2xw, g2yw, nullptr, nullptr,
        g2xas, g2xad, g2yas, g2yad,
        u1, u3,
        ssx, sdx, ssy, sdy,
        nullptr, nullptr, N, gG);
    gat_aggregate2<<<2 * gA, 256, 0, stream>>>(
        offx, csx, ssx, sdx, (const unsigned char*)u1, g2xb, u0,
        offy, csy, ssy, sdy, (const unsigned char*)u3, g2yb, u2,
        N, 0, gA);

    // ---- fusion fc + log_softmax (MFMA, 16 rows/block) ----
    fc_logsoftmax<<<(N + 15) / 16, 64, 0, stream>>>(u0, u2, u4, wbf, fcb, outp, N);
}

// Round 22
// 221.951 us; speedup vs baseline: 1.2842x; 1.0030x over previous
//
#include <hip/hip_runtime.h>
#include <hip/hip_bf16.h>
#include <hip/hip_fp16.h>

#define NEG_SLOPE 0.2f
#define LOG_R 10
#define RPB (1 << LOG_R)      // dsts per coarse bucket
#define EPB 4096              // edges per bucket_pass block
#define CAPB 24576            // fine_sort LDS staging entries

typedef __attribute__((ext_vector_type(4))) float f32x4;
typedef __attribute__((ext_vector_type(2))) float f32x2;
typedef __attribute__((ext_vector_type(8))) short s16x8;

static __device__ __forceinline__ unsigned pkbf(float a, float b) {
    unsigned ua = __float_as_uint(a);
    ua = (ua + 0x7FFFu + ((ua >> 16) & 1u)) >> 16;
    unsigned ub = __float_as_uint(b);
    ub = (ub + 0x7FFFu + ((ub >> 16) & 1u)) & 0xFFFF0000u;
    return (ua & 0xFFFFu) | ub;
}
static __device__ __forceinline__ unsigned short bf1(float a) {
    unsigned ua = __float_as_uint(a);
    return (unsigned short)((ua + 0x7FFFu + ((ua >> 16) & 1u)) >> 16);
}
static __device__ __forceinline__ float bflo(unsigned u) { return __uint_as_float(u << 16); }
static __device__ __forceinline__ float bfhi(unsigned u) { return __uint_as_float(u & 0xFFFF0000u); }

// both MHA weight-combines in one kernel
__global__ __launch_bounds__(256) void mha_combine2(
    const float* __restrict__ iw1, const float* __restrict__ ib1,
    const float* __restrict__ ow1, const float* __restrict__ ob1,
    const float* __restrict__ iw2, const float* __restrict__ ib2,
    const float* __restrict__ ow2, const float* __restrict__ ob2,
    float* __restrict__ cw1, float* __restrict__ cb1,
    float* __restrict__ cw2, float* __restrict__ cb2)
{
    int idx = blockIdx.x * blockDim.x + threadIdx.x;
    int set = idx >> 14;
    int local = idx & 16383;
    int o = local >> 7, i = local & 127;
    const float* in_w  = set ? iw2 : iw1;
    const float* in_b  = set ? ib2 : ib1;
    const float* out_w = set ? ow2 : ow1;
    const float* out_b = set ? ob2 : ob1;
    float* combW = set ? cw2 : cw1;
    float* combb = set ? cb2 : cb1;
    float a = 0.f;
    for (int k = 0; k < 128; ++k)
        a = fmaf(out_w[o * 128 + k], in_w[(256 + k) * 128 + i], a);
    combW[local] = a;
    if (i == 0) {
        float b = out_b[o];
        for (int k = 0; k < 128; ++k)
            b = fmaf(out_w[o * 128 + k], in_b[256 + k], b);
        combb[o] = b;
    }
}

// fold MHA into GAT1: W1 = g1w @ cw, b1 = g1w . cb  (x and y sets)
__global__ __launch_bounds__(256) void wcomb2(
    const float* __restrict__ g1w,
    const float* __restrict__ cw1, const float* __restrict__ cb1,
    const float* __restrict__ cw2, const float* __restrict__ cb2,
    float* __restrict__ w1x, float* __restrict__ b1x,
    float* __restrict__ w1y, float* __restrict__ b1y)
{
    int idx = blockIdx.x * blockDim.x + threadIdx.x;
    if (idx >= 2 * 16384) return;
    int set = idx >> 14;
    int local = idx & 16383;
    int o = local >> 7, i = local & 127;
    const float* cw = set ? cw2 : cw1;
    const float* cb = set ? cb2 : cb1;
    float* wo = set ? w1y : w1x;
    float* bo = set ? b1y : b1x;
    float a = 0.f;
    for (int k = 0; k < 128; ++k)
        a = fmaf(g1w[o * 128 + k], cw[k * 128 + i], a);
    wo[local] = a;
    if (i == 0) {
        float b = 0.f;
        for (int k = 0; k < 128; ++k)
            b = fmaf(g1w[o * 128 + k], cb[k], b);
        bo[o] = b;
    }
}

// fc weight prep: f32 [40][384] -> packed bf16 [48][384] (rows 40..47 zero);
// also zeroes the 128-int coarse-bucket counters (replaces hipMemsetAsync).
__global__ __launch_bounds__(256) void fcw_prep(
    const float* __restrict__ fcw, unsigned* __restrict__ wbf,
    int* __restrict__ bc)
{
    int i = blockIdx.x * 256 + threadIdx.x;
    if (i < 128) bc[i] = 0;
    if (i >= 48 * 192) return;
    unsigned v = 0;
    if (i < 40 * 192) {
        float2 f = ((const float2*)fcw)[i];
        v = pkbf(f.x, f.y);
    }
    wbf[i] = v;
}

// Fused two-graph MFMA GEMM (R16 structure): 64 rows/block, 4 waves;
// A 16 KB + W 32 KB LDS. HFP8: store h as fp8 e4m3; else bf16.
// ao*: optional packed-bf16 copy of the staged A input (saves x->bf16 for fc).
template<bool ABF, bool HFP8>
__global__ __launch_bounds__(256) void gemm_mfma2(
    const void* __restrict__ A0, const void* __restrict__ A1,
    const float* __restrict__ W0, const float* __restrict__ W1,
    const float* __restrict__ bias0, const float* __restrict__ bias1,
    const float* __restrict__ as0, const float* __restrict__ ad0,
    const float* __restrict__ as1, const float* __restrict__ ad1,
    void* __restrict__ h0, void* __restrict__ h1,
    float* __restrict__ ss0, float* __restrict__ sd0,
    float* __restrict__ ss1, float* __restrict__ sd1,
    unsigned* __restrict__ ao0, unsigned* __restrict__ ao1,
    int n, int half)
{
    __shared__ unsigned xl[64 * 64];    // A tile bf16 pairs, 16 KB
    __shared__ unsigned wl[128 * 64];   // W bf16 pairs, 32 KB

    int b = blockIdx.x;
    const void* Ain; const float *W, *bias, *asrc, *adst;
    void* hbs; float *ssrc, *sdst; unsigned* aout;
    if (b < half) { Ain = A0; W = W0; bias = bias0; asrc = as0; adst = ad0; hbs = h0; ssrc = ss0; sdst = sd0; aout = ao0; }
    else { b -= half; Ain = A1; W = W1; bias = bias1; asrc = as1; adst = ad1; hbs = h1; ssrc = ss1; sdst = sd1; aout = ao1; }

    const int t = threadIdx.x;
    const int row0 = b * 64;

#pragma unroll
    for (int i = 0; i < 4; ++i) {
        int q = t + i * 256;
        int r = q >> 4, sl = q & 15;
        int gr = row0 + r; if (gr >= n) gr = n - 1;
        unsigned p0, p1, p2, p3;
        if (ABF) {
            uint4 v = ((const uint4*)Ain)[(size_t)gr * 16 + sl];
            p0 = v.x; p1 = v.y; p2 = v.z; p3 = v.w;
        } else {
            float4 a = ((const float4*)Ain)[(size_t)gr * 32 + sl * 2];
            float4 bb = ((const float4*)Ain)[(size_t)gr * 32 + sl * 2 + 1];
            p0 = pkbf(a.x, a.y); p1 = pkbf(a.z, a.w);
            p2 = pkbf(bb.x, bb.y); p3 = pkbf(bb.z, bb.w);
            if (aout) ((uint4*)aout)[(size_t)gr * 16 + sl] = make_uint4(p0, p1, p2, p3);
        }
        int dsl = sl ^ (r & 7);
        *(uint4*)&xl[r * 64 + dsl * 4] = make_uint4(p0, p1, p2, p3);
    }
#pragma unroll
    for (int i = 0; i < 8; ++i) {
        int q = t + i * 256;
        int r = q >> 4, sl = q & 15;
        float4 a = ((const float4*)W)[(size_t)r * 32 + sl * 2];
        float4 bb = ((const float4*)W)[(size_t)r * 32 + sl * 2 + 1];
        int dsl = sl ^ (r & 7);
        *(uint4*)&wl[r * 64 + dsl * 4] = make_uint4(
            pkbf(a.x, a.y), pkbf(a.z, a.w), pkbf(bb.x, bb.y), pkbf(bb.z, bb.w));
    }
    __syncthreads();

    const int l = t & 63, w = t >> 6;
    const int c = l & 15, q4 = l >> 4;
    const int rloc = w * 16 + c;
    f32x4 acc[8];
#pragma unroll
    for (int nt = 0; nt < 8; ++nt) acc[nt] = (f32x4){0.f, 0.f, 0.f, 0.f};

#pragma unroll
    for (int s = 0; s < 4; ++s) {
        int slot = (s * 4 + q4) ^ (c & 7);
        s16x8 af = *(const s16x8*)&xl[rloc * 64 + slot * 4];
#pragma unroll
        for (int nt = 0; nt < 8; ++nt) {
            int wr = nt * 16 + c;
            s16x8 bfr = *(const s16x8*)&wl[wr * 64 + slot * 4];
            acc[nt] = __builtin_amdgcn_mfma_f32_16x16x32_bf16(af, bfr, acc[nt], 0, 0, 0);
        }
    }

    float bv[8], as8[8], ad8[8];
#pragma unroll
    for (int nt = 0; nt < 8; ++nt) {
        bv[nt]  = bias ? bias[nt * 16 + c] : 0.f;
        as8[nt] = asrc ? asrc[nt * 16 + c] : 0.f;
        ad8[nt] = asrc ? adst[nt * 16 + c] : 0.f;
    }
    float ps[4] = {0.f, 0.f, 0.f, 0.f}, pd[4] = {0.f, 0.f, 0.f, 0.f};
    const int grow0 = row0 + w * 16 + q4 * 4;
#pragma unroll
    for (int nt = 0; nt < 8; ++nt) {
#pragma unroll
        for (int j = 0; j < 4; ++j) {
            float val = acc[nt][j] + bv[nt];
            if (grow0 + j < n) {
                if (HFP8) {
                    unsigned b8 = (unsigned)__builtin_amdgcn_cvt_pk_fp8_f32(val, val, 0, false);
                    ((unsigned char*)hbs)[(size_t)(grow0 + j) * 128 + nt * 16 + c] = (unsigned char)b8;
                } else {
                    ((unsigned short*)hbs)[(size_t)(grow0 + j) * 128 + nt * 16 + c] = bf1(val);
                }
            }
            ps[j] = fmaf(val, as8[nt], ps[j]);
            pd[j] = fmaf(val, ad8[nt], pd[j]);
        }
    }
    if (asrc) {
#pragma unroll
        for (int j = 0; j < 4; ++j) {
            float a = ps[j], bb = pd[j];
#pragma unroll
            for (int o = 1; o < 16; o <<= 1) {
                a += __shfl_xor(a, o);
                bb += __shfl_xor(bb, o);
            }
            if (c == 0 && grow0 + j < n) { ssrc[grow0 + j] = a; sdst[grow0 + j] = bb; }
        }
    }
}

// ---------------- CSR build: two-level bucket sort ----------------

__global__ __launch_bounds__(256) void hist_bucket2(
    const int* __restrict__ eix, const int* __restrict__ eiy, int E, int n,
    int* __restrict__ bcx, int* __restrict__ bcy, int half)
{
    __shared__ int lh[64];
    int gb = blockIdx.x;
    const int* ei = eix; int* bc = bcx;
    if (gb >= half) { gb -= half; ei = eiy; bc = bcy; }
    int t = threadIdx.x;
    int ET = E + n;
    int nbk = (n + RPB - 1) >> LOG_R;
    for (int i = t; i < nbk; i += 256) lh[i] = 0;
    __syncthreads();
    for (int e = gb * 256 + t; e < ET; e += half * 256) {
        int d = (e < E) ? ei[E + e] : (e - E);
        atomicAdd(&lh[d >> LOG_R], 1);
    }
    __syncthreads();
    if (t < nbk) atomicAdd(&bc[t], lh[t]);
}

__global__ void bscan(
    const int* __restrict__ bcx, const int* __restrict__ bcy, int nbk,
    int* __restrict__ bbx, int* __restrict__ bby,
    int* __restrict__ curx, int* __restrict__ cury,
    int* __restrict__ offx_n, int* __restrict__ offy_n)
{
    int w = threadIdx.x >> 6, lane = threadIdx.x & 63;
    if (w > 1) return;
    const int* bc = w ? bcy : bcx;
    int* bb  = w ? bby : bbx;
    int* cur = w ? cury : curx;
    int* offn = w ? offy_n : offx_n;
    int c = (lane < nbk) ? bc[lane] : 0;
    int v = c;
#pragma unroll
    for (int o = 1; o < 64; o <<= 1) {
        int u = __shfl_up(v, o);
        if (lane >= o) v += u;
    }
    int excl = v - c;
    if (lane < nbk) { bb[lane] = excl; cur[lane] = excl; }
    if (lane == 63) { bb[nbk] = v; *offn = v; }
}

// pass A: bucket edges by dst>>LOG_R; per-block LDS sort + contiguous run flush.
__global__ __launch_bounds__(256) void bucket_pass(
    const int* __restrict__ eix, const int* __restrict__ eiy, int E, int n,
    int* __restrict__ curx, int* __restrict__ cury,
    unsigned* __restrict__ pkx, unsigned* __restrict__ pky, int half)
{
    __shared__ int lhist[64], lbase[64], gbase[64], lpos[64];
    __shared__ unsigned stg[EPB];
    __shared__ int gidx[EPB];
    int gb = blockIdx.x;
    const int* ei = eix; int* bcur = curx; unsigned* pk = pkx;
    if (gb >= half) { gb -= half; ei = eiy; bcur = cury; pk = pky; }
    const int t = threadIdx.x;
    const int ET = E + n;
    const int nbk = (n + RPB - 1) >> LOG_R;   // must be <= 64
    const int base = gb * EPB;

    for (int i = t; i < nbk; i += 256) lhist[i] = 0;
    __syncthreads();

    unsigned mypk[16];
    int myb[16];
#pragma unroll
    for (int k = 0; k < 16; ++k) {
        int e = base + k * 256 + t;
        if (e < ET) {
            int s, d;
            if (e < E) { s = ei[e]; d = ei[E + e]; }
            else       { s = e - E; d = e - E; }
            myb[k] = d >> LOG_R;
            mypk[k] = ((unsigned)s << LOG_R) | (unsigned)(d & (RPB - 1));
            atomicAdd(&lhist[myb[k]], 1);
        } else myb[k] = -1;
    }
    __syncthreads();

    if (t < 64) {
        int c = (t < nbk) ? lhist[t] : 0;
        int v = c;
#pragma unroll
        for (int o = 1; o < 64; o <<= 1) {
            int u = __shfl_up(v, o);
            if (t >= o) v += u;
        }
        int excl = v - c;
        if (t < nbk) {
            lbase[t] = excl;
            lpos[t] = excl;
            gbase[t] = c ? atomicAdd(&bcur[t], c) : 0;
        }
    }
    __syncthreads();

#pragma unroll
    for (int k = 0; k < 16; ++k) {
        if (myb[k] >= 0) {
            int p = atomicAdd(&lpos[myb[k]], 1);
            stg[p] = mypk[k];
            gidx[p] = gbase[myb[k]] + (p - lbase[myb[k]]);
        }
    }
    __syncthreads();

    int tot = lbase[nbk - 1] + lhist[nbk - 1];
    for (int i = t; i < tot; i += 256) pk[gidx[i]] = stg[i];
}

// pass B: one block per bucket; per-dst hist + scan (produces off[]), then
// in-LDS scatter and coalesced ushort writeback.
__global__ __launch_bounds__(256) void fine_sort(
    const unsigned* __restrict__ pkx, const unsigned* __restrict__ pky,
    const int* __restrict__ bbx, const int* __restrict__ bby,
    int* __restrict__ offx, int* __restrict__ offy,
    unsigned short* __restrict__ csx, unsigned short* __restrict__ csy,
    int n, int half)
{
    __shared__ int cur[RPB];
    __shared__ int ws[256];
    __shared__ unsigned short outs[CAPB];
    int gb = blockIdx.x;
    const unsigned* pk; const int* bb; int* off; unsigned short* cs;
    if (gb < half) { pk = pkx; bb = bbx; off = offx; cs = csx; }
    else { gb -= half; pk = pky; bb = bby; off = offy; cs = csy; }
    const int t = threadIdx.x;
    const int d0 = gb << LOG_R;
    const int nd = min(RPB, n - d0);
    const int base = bb[gb];
    const int sz = bb[gb + 1] - base;

    for (int i = t; i < RPB; i += 256) cur[i] = 0;
    __syncthreads();
    for (int i = t; i < sz; i += 256)
        atomicAdd(&cur[pk[base + i] & (RPB - 1)], 1);
    __syncthreads();

    int c0 = cur[t * 4], c1 = cur[t * 4 + 1], c2 = cur[t * 4 + 2], c3 = cur[t * 4 + 3];
    int s = c0 + c1 + c2 + c3;
    ws[t] = s; __syncthreads();
    for (int o = 1; o < 256; o <<= 1) {
        int a = (t >= o) ? ws[t - o] : 0;
        __syncthreads();
        ws[t] += a;
        __syncthreads();
    }
    int ex = ws[t] - s;
    int e0 = ex, e1 = ex + c0, e2 = e1 + c1, e3 = e2 + c2;
    cur[t * 4] = e0; cur[t * 4 + 1] = e1; cur[t * 4 + 2] = e2; cur[t * 4 + 3] = e3;
    int i0 = t * 4;
    if (i0     < nd) off[d0 + i0]     = base + e0;
    if (i0 + 1 < nd) off[d0 + i0 + 1] = base + e1;
    if (i0 + 2 < nd) off[d0 + i0 + 2] = base + e2;
    if (i0 + 3 < nd) off[d0 + i0 + 3] = base + e3;
    __syncthreads();

    if (sz <= CAPB) {
        for (int i = t; i < sz; i += 256) {
            unsigned p = pk[base + i];
            int pos = atomicAdd(&cur[p & (RPB - 1)], 1);
            outs[pos] = (unsigned short)(p >> LOG_R);
        }
        __syncthreads();
        for (int i = t; i < sz; i += 256) cs[base + i] = outs[i];
    } else {
        for (int i = t; i < sz; i += 256) {
            unsigned p = pk[base + i];
            int pos = atomicAdd(&cur[p & (RPB - 1)], 1);
            cs[base + pos] = (unsigned short)(p >> LOG_R);
        }
    }
}

// ---------------- fused two-graph GAT aggregation ----------------
// h stored as fp8 e4m3 (128 B/row = 16 lanes x 8 B). FOUR nodes per wave;
// stg padded to 34 entries/node so the 4 quarter-broadcasts hit distinct banks.
__global__ __launch_bounds__(256) void gat_aggregate2(
    const int* __restrict__ off0, const unsigned short* __restrict__ cs0,
    const float* __restrict__ ss0, const float* __restrict__ sd0,
    const unsigned char* __restrict__ hb0, const float* __restrict__ bias0,
    unsigned* __restrict__ out0,
    const int* __restrict__ off1, const unsigned short* __restrict__ cs1,
    const float* __restrict__ ss1, const float* __restrict__ sd1,
    const unsigned char* __restrict__ hb1, const float* __restrict__ bias1,
    unsigned* __restrict__ out1,
    int n, int relu, int half)
{
    __shared__ uint2 stg[4][4][34];
    int b = blockIdx.x;
    const int *off; const unsigned short *csrc; const float *ssrc, *sdst, *bias;
    const unsigned char* hb; unsigned* outu;
    if (b < half) { off = off0; csrc = cs0; ssrc = ss0; sdst = sd0; hb = hb0; bias = bias0; outu = out0; }
    else { b -= half; off = off1; csrc = cs1; ssrc = ss1; sdst = sd1; hb = hb1; bias = bias1; outu = out1; }

    const int w = threadIdx.x >> 6;          // wave in block
    const int lane = threadIdx.x & 63;
    const int qw = lane >> 4;                // quarter-wave = node slot
    const int l16 = lane & 15;
    int node = b * 16 + w * 4 + qw;
    const int valid = node < n;
    if (node >= n) node = n - 1;             // clamp (writes guarded)
    const int p0 = off[node], p1 = off[node + 1];
    const int deg = p1 - p0;
    const float sd = sdst[node];

    // pass A: each lane handles neighbors l16 and l16+16 (exp directly, no max)
    unsigned s0 = 0, s1 = 0;
    float e0 = 0.f, e1 = 0.f;
    if (l16 < deg) {
        s0 = csrc[p0 + l16];
        float v = ssrc[s0] + sd;
        v = (v > 0.f) ? v : NEG_SLOPE * v;
        e0 = __expf(v);
    }
    if (l16 + 16 < deg) {
        s1 = csrc[p0 + 16 + l16];
        float v = ssrc[s1] + sd;
        v = (v > 0.f) ? v : NEG_SLOPE * v;
        e1 = __expf(v);
    }
    float ssum = e0 + e1;
    for (int p = p0 + 32 + l16; p < p1; p += 16) {    // rare deg>32 overflow
        int s = csrc[p];
        float v = ssrc[s] + sd;
        v = (v > 0.f) ? v : NEG_SLOPE * v;
        ssum += __expf(v);
    }
#pragma unroll
    for (int o = 8; o; o >>= 1) ssum += __shfl_xor(ssum, o);

    // stage (src<<7, e) for 32 slots per node; padding entries have e=0
    stg[w][qw][l16]      = make_uint2(s0 << 7, __float_as_uint(e0));
    stg[w][qw][l16 + 16] = make_uint2(s1 << 7, __float_as_uint(e1));

    const unsigned clo = (unsigned)l16 * 8u;          // byte offset: 8 fp8 cols
    float a0 = 0.f, a1 = 0.f, a2 = 0.f, a3 = 0.f;
    float a4 = 0.f, a5 = 0.f, a6 = 0.f, a7 = 0.f;

    int jcap = deg < 32 ? deg : 32;
    int j = 0;
    for (; j + 8 <= jcap; j += 8) {
        uint2 q[8];
#pragma unroll
        for (int k = 0; k < 8; ++k) q[k] = stg[w][qw][j + k];   // broadcast per quarter
        uint2 u[8];
#pragma unroll
        for (int k = 0; k < 8; ++k)
            u[k] = *(const uint2*)(hb + (size_t)(q[k].x | clo));
#pragma unroll
        for (int k = 0; k < 8; ++k) {
            float e = __uint_as_float(q[k].y);
            f32x2 f0 = __builtin_amdgcn_cvt_pk_f32_fp8((int)u[k].x, false);
            f32x2 f1 = __builtin_amdgcn_cvt_pk_f32_fp8((int)u[k].x, true);
            f32x2 f2 = __builtin_amdgcn_cvt_pk_f32_fp8((int)u[k].y, false);
            f32x2 f3 = __builtin_amdgcn_cvt_pk_f32_fp8((int)u[k].y, true);
            a0 = fmaf(e, f0[0], a0); a1 = fmaf(e, f0[1], a1);
            a2 = fmaf(e, f1[0], a2); a3 = fmaf(e, f1[1], a3);
            a4 = fmaf(e, f2[0], a4); a5 = fmaf(e, f2[1], a5);
            a6 = fmaf(e, f3[0], a6); a7 = fmaf(e, f3[1], a7);
        }
    }
    for (; j < jcap; ++j) {
        uint2 q = stg[w][qw][j];
        uint2 u = *(const uint2*)(hb + (size_t)(q.x | clo));
        float e = __uint_as_float(q.y);
        f32x2 f0 = __builtin_amdgcn_cvt_pk_f32_fp8((int)u.x, false);
        f32x2 f1 = __builtin_amdgcn_cvt_pk_f32_fp8((int)u.x, true);
        f32x2 f2 = __builtin_amdgcn_cvt_pk_f32_fp8((int)u.y, false);
        f32x2 f3 = __builtin_amdgcn_cvt_pk_f32_fp8((int)u.y, true);
        a0 = fmaf(e, f0[0], a0); a1 = fmaf(e, f0[1], a1);
        a2 = fmaf(e, f1[0], a2); a3 = fmaf(e, f1[1], a3);
        a4 = fmaf(e, f2[0], a4); a5 = fmaf(e, f2[1], a5);
        a6 = fmaf(e, f3[0], a6); a7 = fmaf(e, f3[1], a7);
    }
    for (int p = p0 + 32; p < p1; ++p) {              // rare deg>32 overflow
        int s = csrc[p];
        float v = ssrc[s] + sd;
        v = (v > 0.f) ? v : NEG_SLOPE * v;
        float e = __expf(v);
        uint2 u = *(const uint2*)(hb + (((size_t)s << 7) | clo));
        f32x2 f0 = __builtin_amdgcn_cvt_pk_f32_fp8((int)u.x, false);
        f32x2 f1 = __builtin_amdgcn_cvt_pk_f32_fp8((int)u.x, true);
        f32x2 f2 = __builtin_amdgcn_cvt_pk_f32_fp8((int)u.y, false);
        f32x2 f3 = __builtin_amdgcn_cvt_pk_f32_fp8((int)u.y, true);
        a0 = fmaf(e, f0[0], a0); a1 = fmaf(e, f0[1], a1);
        a2 = fmaf(e, f1[0], a2); a3 = fmaf(e, f1[1], a3);
        a4 = fmaf(e, f2[0], a4); a5 = fmaf(e, f2[1], a5);
        a6 = fmaf(e, f3[0], a6); a7 = fmaf(e, f3[1], a7);
    }

    float inv = 1.f / (ssum + 1e-16f);
    float4 bva = ((const float4*)bias)[l16 * 2];
    float4 bvb = ((const float4*)bias)[l16 * 2 + 1];
    float o0 = fmaf(a0, inv, bva.x);
    float o1 = fmaf(a1, inv, bva.y);
    float o2 = fmaf(a2, inv, bva.z);
    float o3 = fmaf(a3, inv, bva.w);
    float o4 = fmaf(a4, inv, bvb.x);
    float o5 = fmaf(a5, inv, bvb.y);
    float o6 = fmaf(a6, inv, bvb.z);
    float o7 = fmaf(a7, inv, bvb.w);
    if (relu) {
        o0 = fmaxf(o0, 0.f); o1 = fmaxf(o1, 0.f);
        o2 = fmaxf(o2, 0.f); o3 = fmaxf(o3, 0.f);
        o4 = fmaxf(o4, 0.f); o5 = fmaxf(o5, 0.f);
        o6 = fmaxf(o6, 0.f); o7 = fmaxf(o7, 0.f);
    }
    if (valid)
        ((uint4*)(outu + (size_t)node * 64))[l16] =
            make_uint4(pkbf(o0, o1), pkbf(o2, o3), pkbf(o4, o5), pkbf(o6, o7));
}

// ---------------- MFMA fc + log_softmax: 16 rows/block, 1 wave, K=384, N pad 48 ----------------
__global__ __launch_bounds__(64) void fc_logsoftmax(
    const unsigned* __restrict__ oxu, const unsigned* __restrict__ oyu,
    const unsigned* __restrict__ xbf,
    const unsigned* __restrict__ wbf, const float* __restrict__ fcb,
    float* __restrict__ out, int n)
{
    __shared__ unsigned xl[16 * 192];   // 12 KB: 16 rows x 48 uint4-slots
    const int t = threadIdx.x;
    const int row0 = blockIdx.x * 16;

#pragma unroll
    for (int i = 0; i < 12; ++i) {
        int q = t + i * 64;
        int r = q / 48, sl = q % 48;
        int gr = row0 + r; if (gr >= n) gr = n - 1;
        const unsigned* S = (sl < 16) ? oxu : ((sl < 32) ? oyu : xbf);
        int slo = (sl < 16) ? sl : ((sl < 32) ? sl - 16 : sl - 32);
        uint4 v = ((const uint4*)S)[(size_t)gr * 16 + slo];
        int dsl = sl ^ (r & 7);
        *(uint4*)&xl[r * 192 + dsl * 4] = v;
    }
    __syncthreads();

    const int c = t & 15, q4 = t >> 4;   // single wave: rows 0..15
    f32x4 acc[3];
#pragma unroll
    for (int nt = 0; nt < 3; ++nt) acc[nt] = (f32x4){0.f, 0.f, 0.f, 0.f};

#pragma unroll
    for (int ks = 0; ks < 12; ++ks) {
        int gslot = ks * 4 + q4;
        int slot = gslot ^ (c & 7);
        s16x8 af = *(const s16x8*)&xl[c * 192 + slot * 4];
#pragma unroll
        for (int nt = 0; nt < 3; ++nt) {
            int wr = nt * 16 + c;
            s16x8 bfr = *(const s16x8*)&wbf[(size_t)wr * 192 + gslot * 4];
            acc[nt] = __builtin_amdgcn_mfma_f32_16x16x32_bf16(af, bfr, acc[nt], 0, 0, 0);
        }
    }

    float vb[3];
#pragma unroll
    for (int nt = 0; nt < 3; ++nt) {
        int col = nt * 16 + c;
        vb[nt] = (col < 40) ? fcb[col] : 0.f;
    }
    const int grow0 = row0 + q4 * 4;
#pragma unroll
    for (int j = 0; j < 4; ++j) {
        float v0 = acc[0][j] + vb[0];
        float v1 = acc[1][j] + vb[1];
        float v2 = (c < 8) ? (acc[2][j] + vb[2]) : -INFINITY;
        float m0 = fmaxf(fmaxf(v0, v1), v2);
#pragma unroll
        for (int o = 1; o < 16; o <<= 1) m0 = fmaxf(m0, __shfl_xor(m0, o));
        float s0 = __expf(v0 - m0) + __expf(v1 - m0) + ((c < 8) ? __expf(v2 - m0) : 0.f);
#pragma unroll
        for (int o = 1; o < 16; o <<= 1) s0 += __shfl_xor(s0, o);
        float lse = m0 + logf(s0);
        int grow = grow0 + j;
        if (grow < n) {
            out[(size_t)grow * 40 + c] = v0 - lse;
            out[(size_t)grow * 40 + 16 + c] = v1 - lse;
            if (c < 8) out[(size_t)grow * 40 + 32 + c] = v2 - lse;
        }
    }
}

extern "C" void kernel_launch(void* const* d_in, const int* in_sizes, int n_in,
                              void* d_out, int out_size, void* d_ws, size_t ws_size,
                              hipStream_t stream)
{
    const float* x    = (const float*)d_in[0];
    const float* y    = (const float*)d_in[1];
    const int*   eix  = (const int*)d_in[2];
    const int*   eiy  = (const int*)d_in[3];
    const float* a1iw = (const float*)d_in[4];
    const float* a1ib = (const float*)d_in[5];
    const float* a1ow = (const float*)d_in[6];
    const float* a1ob = (const float*)d_in[7];
    const float* a2iw = (const float*)d_in[8];
    const float* a2ib = (const float*)d_in[9];
    const float* a2ow = (const float*)d_in[10];
    const float* a2ob = (const float*)d_in[11];
    const float* g1w  = (const float*)d_in[12];
    const float* g1as = (const float*)d_in[13];
    const float* g1ad = (const float*)d_in[14];
    const float* g1b  = (const float*)d_in[15];
    const float* g2xw = (const float*)d_in[16];
    const float* g2xas= (const float*)d_in[17];
    const float* g2xad= (const float*)d_in[18];
    const float* g2xb = (const float*)d_in[19];
    const float* g2yw = (const float*)d_in[20];
    const float* g2yas= (const float*)d_in[21];
    const float* g2yad= (const float*)d_in[22];
    const float* g2yb = (const float*)d_in[23];
    const float* fcw  = (const float*)d_in[24];
    const float* fcb  = (const float*)d_in[25];
    float* outp = (float*)d_out;

    const int N = in_sizes[0] / 128;
    const int E = in_sizes[2] / 2;
    (void)n_in; (void)out_size; (void)ws_size;

    size_t NU = (size_t)N * 64;              // uints per packed node buffer
    unsigned* u0 = (unsigned*)d_ws;          // r1x -> ox  (bf16 packed)
    unsigned* u1 = u0 + NU;                  // hx (fp8, N*32 used)
    unsigned* u2 = u1 + NU;                  // r1y -> oy  (bf16 packed)
    unsigned* u3 = u2 + NU;                  // hy (fp8, N*32 used)
    unsigned* u4 = u3 + NU;                  // x residual, bf16 packed
    float* ssx = (float*)(u4 + NU);
    float* sdx = ssx + N;
    float* ssy = sdx + N;
    float* sdy = ssy + N;
    float* cw1 = sdy + N;
    float* cb1 = cw1 + 128 * 128;
    float* cw2 = cb1 + 128;
    float* cb2 = cw2 + 128 * 128;
    const int Npad = (N + 4) & ~3;
    int* offx = (int*)(cb2 + 128);           // N+1
    int* offy = offx + Npad;
    int* bbx  = offy + Npad;                 // nbk+1 (<=65), pad 128
    int* bby  = bbx + 128;
    int* bcx  = bby + 128;                   // 64
    int* bcy  = bcx + 64;
    int* curx = bcy + 64;                    // 64
    int* cury = curx + 64;
    unsigned* pkx = (unsigned*)(cury + 64);  // E+N packed entries
    unsigned* pky = pkx + (E + N);
    unsigned short* csx = (unsigned short*)(pky + (E + N));   // E+N ushort
    unsigned short* csy = csx + (((E + N) + 1) & ~1);
    unsigned* wbf = (unsigned*)(csy + (((E + N) + 1) & ~1));  // 48*192 uints
    float* w1cx = (float*)(wbf + 48 * 192);  // 16384 (fused GAT1 weight, x)
    float* b1cx = w1cx + 16384;              // 128
    float* w1cy = b1cx + 128;                // 16384
    float* b1cy = w1cy + 16384;              // 128

    const int ET = E + N;
    const int NBK = (N + RPB - 1) >> LOG_R;  // <= 64 required (N <= 65536)
    const int gG = (N + 63) / 64;
    const int gA = (N + 15) / 16;
    const int nAB = (ET + EPB - 1) / EPB;

    mha_combine2<<<128, 256, 0, stream>>>(a1iw, a1ib, a1ow, a1ob,
                                          a2iw, a2ib, a2ow, a2ob,
                                          cw1, cb1, cw2, cb2);
    wcomb2<<<128, 256, 0, stream>>>(g1w, cw1, cb1, cw2, cb2,
                                    w1cx, b1cx, w1cy, b1cy);
    fcw_prep<<<(48 * 192 + 255) / 256, 256, 0, stream>>>(fcw, wbf, bcx);

    // ---- build both CSRs (two-level bucket sort) ----
    hist_bucket2<<<256, 256, 0, stream>>>(eix, eiy, E, N, bcx, bcy, 128);
    bscan<<<1, 128, 0, stream>>>(bcx, bcy, NBK, bbx, bby, curx, cury, offx + N, offy + N);
    bucket_pass<<<2 * nAB, 256, 0, stream>>>(eix, eiy, E, N, curx, cury, pkx, pky, nAB);
    fine_sort<<<2 * NBK, 256, 0, stream>>>(pkx, pky, bbx, bby, offx, offy, csx, csy, N, NBK);

    // ---- fused MHA+GAT1 GEMM (both): x f32 -> fp8 h (+ x saved as bf16) ----
    gemm_mfma2<false, true><<<2 * gG, 256, 0, stream>>>(
        x, y, w1cx, w1cy, b1cx, b1cy,
        g1as, g1ad, g1as, g1ad,
        u1, u3,
        ssx, sdx, ssy, sdy,
        u4, nullptr, N, gG);
    gat_aggregate2<<<2 * gA, 256, 0, stream>>>(
        offx, csx, ssx, sdx, (const unsigned char*)u1, g1b, u0,
        offy, csy, ssy, sdy, (const unsigned char*)u3, g1b, u2,
        N, 1, gA);

    // ---- GAT layer 2 (both) ----
    gemm_mfma2<true, true><<<2 * gG, 256, 0, stream>>>(
        u0, u2, g2xw, g2yw, nullptr, nullptr,
        g2xas, g2xad, g2yas, g2yad,
        u1, u3,
        ssx, sdx, ssy, sdy,
        nullptr, nullptr, N, gG);
    gat_aggregate2<<<2 * gA, 256, 0, stream>>>(
        offx, csx, ssx, sdx, (const unsigned char*)u1, g2xb, u0,
        offy, csy, ssy, sdy, (const unsigned char*)u3, g2yb, u2,
        N, 0, gA);

    // ---- fusion fc + log_softmax (MFMA, 16 rows/block) ----
    fc_logsoftmax<<<(N + 15) / 16, 64, 0, stream>>>(u0, u2, u4, wbf, fcb, outp, N);
}

// Round 23
// 220.670 us; speedup vs baseline: 1.2917x; 1.0058x over previous
//
#include <hip/hip_runtime.h>
#include <hip/hip_bf16.h>
#include <hip/hip_fp16.h>

#define NEG_SLOPE 0.2f
#define LOG_R 10
#define RPB (1 << LOG_R)      // dsts per coarse bucket
#define EPB 4096              // edges per bucket_pass block
#define CAPB 24576            // fine_sort LDS staging entries

typedef __attribute__((ext_vector_type(4))) float f32x4;
typedef __attribute__((ext_vector_type(2))) float f32x2;
typedef __attribute__((ext_vector_type(8))) short s16x8;

static __device__ __forceinline__ unsigned pkbf(float a, float b) {
    unsigned ua = __float_as_uint(a);
    ua = (ua + 0x7FFFu + ((ua >> 16) & 1u)) >> 16;
    unsigned ub = __float_as_uint(b);
    ub = (ub + 0x7FFFu + ((ub >> 16) & 1u)) & 0xFFFF0000u;
    return (ua & 0xFFFFu) | ub;
}
static __device__ __forceinline__ float bflo(unsigned u) { return __uint_as_float(u << 16); }
static __device__ __forceinline__ float bfhi(unsigned u) { return __uint_as_float(u & 0xFFFF0000u); }

// both MHA weight-combines in one kernel
__global__ __launch_bounds__(256) void mha_combine2(
    const float* __restrict__ iw1, const float* __restrict__ ib1,
    const float* __restrict__ ow1, const float* __restrict__ ob1,
    const float* __restrict__ iw2, const float* __restrict__ ib2,
    const float* __restrict__ ow2, const float* __restrict__ ob2,
    float* __restrict__ cw1, float* __restrict__ cb1,
    float* __restrict__ cw2, float* __restrict__ cb2)
{
    int idx = blockIdx.x * blockDim.x + threadIdx.x;
    int set = idx >> 14;
    int local = idx & 16383;
    int o = local >> 7, i = local & 127;
    const float* in_w  = set ? iw2 : iw1;
    const float* in_b  = set ? ib2 : ib1;
    const float* out_w = set ? ow2 : ow1;
    const float* out_b = set ? ob2 : ob1;
    float* combW = set ? cw2 : cw1;
    float* combb = set ? cb2 : cb1;
    float a = 0.f;
    for (int k = 0; k < 128; ++k)
        a = fmaf(out_w[o * 128 + k], in_w[(256 + k) * 128 + i], a);
    combW[local] = a;
    if (i == 0) {
        float b = out_b[o];
        for (int k = 0; k < 128; ++k)
            b = fmaf(out_w[o * 128 + k], in_b[256 + k], b);
        combb[o] = b;
    }
}

// fold MHA into GAT1: W1 = g1w @ cw, b1 = g1w . cb  (x and y sets)
__global__ __launch_bounds__(256) void wcomb2(
    const float* __restrict__ g1w,
    const float* __restrict__ cw1, const float* __restrict__ cb1,
    const float* __restrict__ cw2, const float* __restrict__ cb2,
    float* __restrict__ w1x, float* __restrict__ b1x,
    float* __restrict__ w1y, float* __restrict__ b1y)
{
    int idx = blockIdx.x * blockDim.x + threadIdx.x;
    if (idx >= 2 * 16384) return;
    int set = idx >> 14;
    int local = idx & 16383;
    int o = local >> 7, i = local & 127;
    const float* cw = set ? cw2 : cw1;
    const float* cb = set ? cb2 : cb1;
    float* wo = set ? w1y : w1x;
    float* bo = set ? b1y : b1x;
    float a = 0.f;
    for (int k = 0; k < 128; ++k)
        a = fmaf(g1w[o * 128 + k], cw[k * 128 + i], a);
    wo[local] = a;
    if (i == 0) {
        float b = 0.f;
        for (int k = 0; k < 128; ++k)
            b = fmaf(g1w[o * 128 + k], cb[k], b);
        bo[o] = b;
    }
}

// pack the four GEMM weights (w1x, w1y, g2xw, g2yw) -> bf16 pairs [4][128][64]
__global__ __launch_bounds__(256) void wpack4(
    const float* __restrict__ w1x, const float* __restrict__ w1y,
    const float* __restrict__ g2xw, const float* __restrict__ g2yw,
    unsigned* __restrict__ wp)
{
    int i = blockIdx.x * 256 + threadIdx.x;
    if (i >= 4 * 8192) return;
    int m = i >> 13, loc = i & 8191;
    const float* src = (m == 0) ? w1x : (m == 1) ? w1y : (m == 2) ? g2xw : g2yw;
    float2 f = ((const float2*)src)[loc];
    wp[i] = pkbf(f.x, f.y);
}

// fc weight prep: f32 [40][384] -> packed bf16 [48][384] (rows 40..47 zero);
// also zeroes the 128-int coarse-bucket counters (replaces hipMemsetAsync).
__global__ __launch_bounds__(256) void fcw_prep(
    const float* __restrict__ fcw, unsigned* __restrict__ wbf,
    int* __restrict__ bc)
{
    int i = blockIdx.x * 256 + threadIdx.x;
    if (i < 128) bc[i] = 0;
    if (i >= 48 * 192) return;
    unsigned v = 0;
    if (i < 40 * 192) {
        float2 f = ((const float2*)fcw)[i];
        v = pkbf(f.x, f.y);
    }
    wbf[i] = v;
}

// Fused two-graph MFMA GEMM: 64 rows/block, 4 waves; A 16 KB + W 32 KB LDS.
// W read from pre-packed bf16 global (pure uint4 copies into LDS).
// Output: fp8 e4m3 h, written via per-wave LDS bounce -> fully coalesced
// 256 B dword bursts (kills partial-sector write amplification).
// ao*: optional packed-bf16 copy of the staged A input (saves x->bf16 for fc).
template<bool ABF>
__global__ __launch_bounds__(256) void gemm_mfma2(
    const void* __restrict__ A0, const void* __restrict__ A1,
    const unsigned* __restrict__ Wp0, const unsigned* __restrict__ Wp1,
    const float* __restrict__ bias0, const float* __restrict__ bias1,
    const float* __restrict__ as0, const float* __restrict__ ad0,
    const float* __restrict__ as1, const float* __restrict__ ad1,
    unsigned char* __restrict__ h0, unsigned char* __restrict__ h1,
    float* __restrict__ ss0, float* __restrict__ sd0,
    float* __restrict__ ss1, float* __restrict__ sd1,
    unsigned* __restrict__ ao0, unsigned* __restrict__ ao1,
    int n, int half)
{
    __shared__ unsigned xl[64 * 64];    // A tile bf16 pairs (16 KB); reused per-wave for fp8 out
    __shared__ unsigned wl[128 * 64];   // W bf16 pairs, 32 KB

    int b = blockIdx.x;
    const void* Ain; const unsigned* Wp; const float *bias, *asrc, *adst;
    unsigned char* hbs; float *ssrc, *sdst; unsigned* aout;
    if (b < half) { Ain = A0; Wp = Wp0; bias = bias0; asrc = as0; adst = ad0; hbs = h0; ssrc = ss0; sdst = sd0; aout = ao0; }
    else { b -= half; Ain = A1; Wp = Wp1; bias = bias1; asrc = as1; adst = ad1; hbs = h1; ssrc = ss1; sdst = sd1; aout = ao1; }

    const int t = threadIdx.x;
    const int row0 = b * 64;

#pragma unroll
    for (int i = 0; i < 4; ++i) {
        int q = t + i * 256;
        int r = q >> 4, sl = q & 15;
        int gr = row0 + r; if (gr >= n) gr = n - 1;
        unsigned p0, p1, p2, p3;
        if (ABF) {
            uint4 v = ((const uint4*)Ain)[(size_t)gr * 16 + sl];
            p0 = v.x; p1 = v.y; p2 = v.z; p3 = v.w;
        } else {
            float4 a = ((const float4*)Ain)[(size_t)gr * 32 + sl * 2];
            float4 bb = ((const float4*)Ain)[(size_t)gr * 32 + sl * 2 + 1];
            p0 = pkbf(a.x, a.y); p1 = pkbf(a.z, a.w);
            p2 = pkbf(bb.x, bb.y); p3 = pkbf(bb.z, bb.w);
            if (aout) ((uint4*)aout)[(size_t)gr * 16 + sl] = make_uint4(p0, p1, p2, p3);
        }
        int dsl = sl ^ (r & 7);
        *(uint4*)&xl[r * 64 + dsl * 4] = make_uint4(p0, p1, p2, p3);
    }
#pragma unroll
    for (int i = 0; i < 8; ++i) {
        int q = t + i * 256;
        int r = q >> 4, sl = q & 15;
        uint4 v = ((const uint4*)Wp)[r * 16 + sl];
        int dsl = sl ^ (r & 7);
        *(uint4*)&wl[r * 64 + dsl * 4] = v;
    }
    __syncthreads();

    const int l = t & 63, w = t >> 6;
    const int c = l & 15, q4 = l >> 4;
    const int rloc = w * 16 + c;
    f32x4 acc[8];
#pragma unroll
    for (int nt = 0; nt < 8; ++nt) acc[nt] = (f32x4){0.f, 0.f, 0.f, 0.f};

#pragma unroll
    for (int s = 0; s < 4; ++s) {
        int slot = (s * 4 + q4) ^ (c & 7);
        s16x8 af = *(const s16x8*)&xl[rloc * 64 + slot * 4];
#pragma unroll
        for (int nt = 0; nt < 8; ++nt) {
            int wr = nt * 16 + c;
            s16x8 bfr = *(const s16x8*)&wl[wr * 64 + slot * 4];
            acc[nt] = __builtin_amdgcn_mfma_f32_16x16x32_bf16(af, bfr, acc[nt], 0, 0, 0);
        }
    }

    float bv[8], as8[8], ad8[8];
#pragma unroll
    for (int nt = 0; nt < 8; ++nt) {
        bv[nt]  = bias ? bias[nt * 16 + c] : 0.f;
        as8[nt] = asrc ? asrc[nt * 16 + c] : 0.f;
        ad8[nt] = asrc ? adst[nt * 16 + c] : 0.f;
    }
    float ps[4] = {0.f, 0.f, 0.f, 0.f}, pd[4] = {0.f, 0.f, 0.f, 0.f};
    const int grow0 = row0 + w * 16 + q4 * 4;

    // pack fp8 bytes into this wave's private (already-consumed) xl quarter
    unsigned char* op = (unsigned char*)&xl[w * 1024];
#pragma unroll
    for (int nt = 0; nt < 8; ++nt) {
#pragma unroll
        for (int j = 0; j < 4; ++j) {
            float val = acc[nt][j] + bv[nt];
            unsigned b8 = (unsigned)__builtin_amdgcn_cvt_pk_fp8_f32(val, val, 0, false);
            op[(q4 * 4 + j) * 128 + nt * 16 + c] = (unsigned char)b8;
            ps[j] = fmaf(val, as8[nt], ps[j]);
            pd[j] = fmaf(val, ad8[nt], pd[j]);
        }
    }
    // coalesced writeback: 16 rows x 128 B = 512 dwords per wave
    {
        const unsigned* src = &xl[w * 1024];
        unsigned* dst = (unsigned*)(hbs + (size_t)(row0 + w * 16) * 128);
#pragma unroll
        for (int i = 0; i < 8; ++i) {
            int idx = i * 64 + l;
            int grow = row0 + w * 16 + (idx >> 5);
            if (grow < n) dst[idx] = src[idx];
        }
    }

    if (asrc) {
#pragma unroll
        for (int j = 0; j < 4; ++j) {
            float a = ps[j], bb = pd[j];
#pragma unroll
            for (int o = 1; o < 16; o <<= 1) {
                a += __shfl_xor(a, o);
                bb += __shfl_xor(bb, o);
            }
            if (c == 0 && grow0 + j < n) { ssrc[grow0 + j] = a; sdst[grow0 + j] = bb; }
        }
    }
}

// ---------------- CSR build: two-level bucket sort ----------------

__global__ __launch_bounds__(256) void hist_bucket2(
    const int* __restrict__ eix, const int* __restrict__ eiy, int E, int n,
    int* __restrict__ bcx, int* __restrict__ bcy, int half)
{
    __shared__ int lh[64];
    int gb = blockIdx.x;
    const int* ei = eix; int* bc = bcx;
    if (gb >= half) { gb -= half; ei = eiy; bc = bcy; }
    int t = threadIdx.x;
    int ET = E + n;
    int nbk = (n + RPB - 1) >> LOG_R;
    for (int i = t; i < nbk; i += 256) lh[i] = 0;
    __syncthreads();
    for (int e = gb * 256 + t; e < ET; e += half * 256) {
        int d = (e < E) ? ei[E + e] : (e - E);
        atomicAdd(&lh[d >> LOG_R], 1);
    }
    __syncthreads();
    if (t < nbk) atomicAdd(&bc[t], lh[t]);
}

__global__ void bscan(
    const int* __restrict__ bcx, const int* __restrict__ bcy, int nbk,
    int* __restrict__ bbx, int* __restrict__ bby,
    int* __restrict__ curx, int* __restrict__ cury,
    int* __restrict__ offx_n, int* __restrict__ offy_n)
{
    int w = threadIdx.x >> 6, lane = threadIdx.x & 63;
    if (w > 1) return;
    const int* bc = w ? bcy : bcx;
    int* bb  = w ? bby : bbx;
    int* cur = w ? cury : curx;
    int* offn = w ? offy_n : offx_n;
    int c = (lane < nbk) ? bc[lane] : 0;
    int v = c;
#pragma unroll
    for (int o = 1; o < 64; o <<= 1) {
        int u = __shfl_up(v, o);
        if (lane >= o) v += u;
    }
    int excl = v - c;
    if (lane < nbk) { bb[lane] = excl; cur[lane] = excl; }
    if (lane == 63) { bb[nbk] = v; *offn = v; }
}

// pass A: bucket edges by dst>>LOG_R; per-block LDS sort + contiguous run flush.
__global__ __launch_bounds__(256) void bucket_pass(
    const int* __restrict__ eix, const int* __restrict__ eiy, int E, int n,
    int* __restrict__ curx, int* __restrict__ cury,
    unsigned* __restrict__ pkx, unsigned* __restrict__ pky, int half)
{
    __shared__ int lhist[64], lbase[64], gbase[64], lpos[64];
    __shared__ unsigned stg[EPB];
    __shared__ int gidx[EPB];
    int gb = blockIdx.x;
    const int* ei = eix; int* bcur = curx; unsigned* pk = pkx;
    if (gb >= half) { gb -= half; ei = eiy; bcur = cury; pk = pky; }
    const int t = threadIdx.x;
    const int ET = E + n;
    const int nbk = (n + RPB - 1) >> LOG_R;   // must be <= 64
    const int base = gb * EPB;

    for (int i = t; i < nbk; i += 256) lhist[i] = 0;
    __syncthreads();

    unsigned mypk[16];
    int myb[16];
#pragma unroll
    for (int k = 0; k < 16; ++k) {
        int e = base + k * 256 + t;
        if (e < ET) {
            int s, d;
            if (e < E) { s = ei[e]; d = ei[E + e]; }
            else       { s = e - E; d = e - E; }
            myb[k] = d >> LOG_R;
            mypk[k] = ((unsigned)s << LOG_R) | (unsigned)(d & (RPB - 1));
            atomicAdd(&lhist[myb[k]], 1);
        } else myb[k] = -1;
    }
    __syncthreads();

    if (t < 64) {
        int c = (t < nbk) ? lhist[t] : 0;
        int v = c;
#pragma unroll
        for (int o = 1; o < 64; o <<= 1) {
            int u = __shfl_up(v, o);
            if (t >= o) v += u;
        }
        int excl = v - c;
        if (t < nbk) {
            lbase[t] = excl;
            lpos[t] = excl;
            gbase[t] = c ? atomicAdd(&bcur[t], c) : 0;
        }
    }
    __syncthreads();

#pragma unroll
    for (int k = 0; k < 16; ++k) {
        if (myb[k] >= 0) {
            int p = atomicAdd(&lpos[myb[k]], 1);
            stg[p] = mypk[k];
            gidx[p] = gbase[myb[k]] + (p - lbase[myb[k]]);
        }
    }
    __syncthreads();

    int tot = lbase[nbk - 1] + lhist[nbk - 1];
    for (int i = t; i < tot; i += 256) pk[gidx[i]] = stg[i];
}

// pass B: one block per bucket; per-dst hist + scan (produces off[]), then
// in-LDS scatter and coalesced ushort writeback.
__global__ __launch_bounds__(256) void fine_sort(
    const unsigned* __restrict__ pkx, const unsigned* __restrict__ pky,
    const int* __restrict__ bbx, const int* __restrict__ bby,
    int* __restrict__ offx, int* __restrict__ offy,
    unsigned short* __restrict__ csx, unsigned short* __restrict__ csy,
    int n, int half)
{
    __shared__ int cur[RPB];
    __shared__ int ws[256];
    __shared__ unsigned short outs[CAPB];
    int gb = blockIdx.x;
    const unsigned* pk; const int* bb; int* off; unsigned short* cs;
    if (gb < half) { pk = pkx; bb = bbx; off = offx; cs = csx; }
    else { gb -= half; pk = pky; bb = bby; off = offy; cs = csy; }
    const int t = threadIdx.x;
    const int d0 = gb << LOG_R;
    const int nd = min(RPB, n - d0);
    const int base = bb[gb];
    const int sz = bb[gb + 1] - base;

    for (int i = t; i < RPB; i += 256) cur[i] = 0;
    __syncthreads();
    for (int i = t; i < sz; i += 256)
        atomicAdd(&cur[pk[base + i] & (RPB - 1)], 1);
    __syncthreads();

    int c0 = cur[t * 4], c1 = cur[t * 4 + 1], c2 = cur[t * 4 + 2], c3 = cur[t * 4 + 3];
    int s = c0 + c1 + c2 + c3;
    ws[t] = s; __syncthreads();
    for (int o = 1; o < 256; o <<= 1) {
        int a = (t >= o) ? ws[t - o] : 0;
        __syncthreads();
        ws[t] += a;
        __syncthreads();
    }
    int ex = ws[t] - s;
    int e0 = ex, e1 = ex + c0, e2 = e1 + c1, e3 = e2 + c2;
    cur[t * 4] = e0; cur[t * 4 + 1] = e1; cur[t * 4 + 2] = e2; cur[t * 4 + 3] = e3;
    int i0 = t * 4;
    if (i0     < nd) off[d0 + i0]     = base + e0;
    if (i0 + 1 < nd) off[d0 + i0 + 1] = base + e1;
    if (i0 + 2 < nd) off[d0 + i0 + 2] = base + e2;
    if (i0 + 3 < nd) off[d0 + i0 + 3] = base + e3;
    __syncthreads();

    if (sz <= CAPB) {
        for (int i = t; i < sz; i += 256) {
            unsigned p = pk[base + i];
            int pos = atomicAdd(&cur[p & (RPB - 1)], 1);
            outs[pos] = (unsigned short)(p >> LOG_R);
        }
        __syncthreads();
        for (int i = t; i < sz; i += 256) cs[base + i] = outs[i];
    } else {
        for (int i = t; i < sz; i += 256) {
            unsigned p = pk[base + i];
            int pos = atomicAdd(&cur[p & (RPB - 1)], 1);
            cs[base + pos] = (unsigned short)(p >> LOG_R);
        }
    }
}

// ---------------- fused two-graph GAT aggregation ----------------
// h stored as fp8 e4m3 (128 B/row = 16 lanes x 8 B). FOUR nodes per wave;
// stg padded to 34 entries/node so the 4 quarter-broadcasts hit distinct banks.
__global__ __launch_bounds__(256) void gat_aggregate2(
    const int* __restrict__ off0, const unsigned short* __restrict__ cs0,
    const float* __restrict__ ss0, const float* __restrict__ sd0,
    const unsigned char* __restrict__ hb0, const float* __restrict__ bias0,
    unsigned* __restrict__ out0,
    const int* __restrict__ off1, const unsigned short* __restrict__ cs1,
    const float* __restrict__ ss1, const float* __restrict__ sd1,
    const unsigned char* __restrict__ hb1, const float* __restrict__ bias1,
    unsigned* __restrict__ out1,
    int n, int relu, int half)
{
    __shared__ uint2 stg[4][4][34];
    int b = blockIdx.x;
    const int *off; const unsigned short *csrc; const float *ssrc, *sdst, *bias;
    const unsigned char* hb; unsigned* outu;
    if (b < half) { off = off0; csrc = cs0; ssrc = ss0; sdst = sd0; hb = hb0; bias = bias0; outu = out0; }
    else { b -= half; off = off1; csrc = cs1; ssrc = ss1; sdst = sd1; hb = hb1; bias = bias1; outu = out1; }

    const int w = threadIdx.x >> 6;          // wave in block
    const int lane = threadIdx.x & 63;
    const int qw = lane >> 4;                // quarter-wave = node slot
    const int l16 = lane & 15;
    int node = b * 16 + w * 4 + qw;
    const int valid = node < n;
    if (node >= n) node = n - 1;             // clamp (writes guarded)
    const int p0 = off[node], p1 = off[node + 1];
    const int deg = p1 - p0;
    const float sd = sdst[node];

    // pass A: each lane handles neighbors l16 and l16+16 (exp directly, no max)
    unsigned s0 = 0, s1 = 0;
    float e0 = 0.f, e1 = 0.f;
    if (l16 < deg) {
        s0 = csrc[p0 + l16];
        float v = ssrc[s0] + sd;
        v = (v > 0.f) ? v : NEG_SLOPE * v;
        e0 = __expf(v);
    }
    if (l16 + 16 < deg) {
        s1 = csrc[p0 + 16 + l16];
        float v = ssrc[s1] + sd;
        v = (v > 0.f) ? v : NEG_SLOPE * v;
        e1 = __expf(v);
    }
    float ssum = e0 + e1;
    for (int p = p0 + 32 + l16; p < p1; p += 16) {    // rare deg>32 overflow
        int s = csrc[p];
        float v = ssrc[s] + sd;
        v = (v > 0.f) ? v : NEG_SLOPE * v;
        ssum += __expf(v);
    }
#pragma unroll
    for (int o = 8; o; o >>= 1) ssum += __shfl_xor(ssum, o);

    // stage (src<<7, e) for 32 slots per node; padding entries have e=0
    stg[w][qw][l16]      = make_uint2(s0 << 7, __float_as_uint(e0));
    stg[w][qw][l16 + 16] = make_uint2(s1 << 7, __float_as_uint(e1));

    const unsigned clo = (unsigned)l16 * 8u;          // byte offset: 8 fp8 cols
    float a0 = 0.f, a1 = 0.f, a2 = 0.f, a3 = 0.f;
    float a4 = 0.f, a5 = 0.f, a6 = 0.f, a7 = 0.f;

    int jcap = deg < 32 ? deg : 32;
    int j = 0;
    for (; j + 8 <= jcap; j += 8) {
        uint2 q[8];
#pragma unroll
        for (int k = 0; k < 8; ++k) q[k] = stg[w][qw][j + k];   // broadcast per quarter
        uint2 u[8];
#pragma unroll
        for (int k = 0; k < 8; ++k)
            u[k] = *(const uint2*)(hb + (size_t)(q[k].x | clo));
#pragma unroll
        for (int k = 0; k < 8; ++k) {
            float e = __uint_as_float(q[k].y);
            f32x2 f0 = __builtin_amdgcn_cvt_pk_f32_fp8((int)u[k].x, false);
            f32x2 f1 = __builtin_amdgcn_cvt_pk_f32_fp8((int)u[k].x, true);
            f32x2 f2 = __builtin_amdgcn_cvt_pk_f32_fp8((int)u[k].y, false);
            f32x2 f3 = __builtin_amdgcn_cvt_pk_f32_fp8((int)u[k].y, true);
            a0 = fmaf(e, f0[0], a0); a1 = fmaf(e, f0[1], a1);
            a2 = fmaf(e, f1[0], a2); a3 = fmaf(e, f1[1], a3);
            a4 = fmaf(e, f2[0], a4); a5 = fmaf(e, f2[1], a5);
            a6 = fmaf(e, f3[0], a6); a7 = fmaf(e, f3[1], a7);
        }
    }
    for (; j < jcap; ++j) {
        uint2 q = stg[w][qw][j];
        uint2 u = *(const uint2*)(hb + (size_t)(q.x | clo));
        float e = __uint_as_float(q.y);
        f32x2 f0 = __builtin_amdgcn_cvt_pk_f32_fp8((int)u.x, false);
        f32x2 f1 = __builtin_amdgcn_cvt_pk_f32_fp8((int)u.x, true);
        f32x2 f2 = __builtin_amdgcn_cvt_pk_f32_fp8((int)u.y, false);
        f32x2 f3 = __builtin_amdgcn_cvt_pk_f32_fp8((int)u.y, true);
        a0 = fmaf(e, f0[0], a0); a1 = fmaf(e, f0[1], a1);
        a2 = fmaf(e, f1[0], a2); a3 = fmaf(e, f1[1], a3);
        a4 = fmaf(e, f2[0], a4); a5 = fmaf(e, f2[1], a5);
        a6 = fmaf(e, f3[0], a6); a7 = fmaf(e, f3[1], a7);
    }
    for (int p = p0 + 32; p < p1; ++p) {              // rare deg>32 overflow
        int s = csrc[p];
        float v = ssrc[s] + sd;
        v = (v > 0.f) ? v : NEG_SLOPE * v;
        float e = __expf(v);
        uint2 u = *(const uint2*)(hb + (((size_t)s << 7) | clo));
        f32x2 f0 = __builtin_amdgcn_cvt_pk_f32_fp8((int)u.x, false);
        f32x2 f1 = __builtin_amdgcn_cvt_pk_f32_fp8((int)u.x, true);
        f32x2 f2 = __builtin_amdgcn_cvt_pk_f32_fp8((int)u.y, false);
        f32x2 f3 = __builtin_amdgcn_cvt_pk_f32_fp8((int)u.y, true);
        a0 = fmaf(e, f0[0], a0); a1 = fmaf(e, f0[1], a1);
        a2 = fmaf(e, f1[0], a2); a3 = fmaf(e, f1[1], a3);
        a4 = fmaf(e, f2[0], a4); a5 = fmaf(e, f2[1], a5);
        a6 = fmaf(e, f3[0], a6); a7 = fmaf(e, f3[1], a7);
    }

    float inv = 1.f / (ssum + 1e-16f);
    float4 bva = ((const float4*)bias)[l16 * 2];
    float4 bvb = ((const float4*)bias)[l16 * 2 + 1];
    float o0 = fmaf(a0, inv, bva.x);
    float o1 = fmaf(a1, inv, bva.y);
    float o2 = fmaf(a2, inv, bva.z);
    float o3 = fmaf(a3, inv, bva.w);
    float o4 = fmaf(a4, inv, bvb.x);
    float o5 = fmaf(a5, inv, bvb.y);
    float o6 = fmaf(a6, inv, bvb.z);
    float o7 = fmaf(a7, inv, bvb.w);
    if (relu) {
        o0 = fmaxf(o0, 0.f); o1 = fmaxf(o1, 0.f);
        o2 = fmaxf(o2, 0.f); o3 = fmaxf(o3, 0.f);
        o4 = fmaxf(o4, 0.f); o5 = fmaxf(o5, 0.f);
        o6 = fmaxf(o6, 0.f); o7 = fmaxf(o7, 0.f);
    }
    if (valid)
        ((uint4*)(outu + (size_t)node * 64))[l16] =
            make_uint4(pkbf(o0, o1), pkbf(o2, o3), pkbf(o4, o5), pkbf(o6, o7));
}

// ---------------- MFMA fc + log_softmax: 16 rows/block, 1 wave, K=384, N pad 48 ----------------
__global__ __launch_bounds__(64) void fc_logsoftmax(
    const unsigned* __restrict__ oxu, const unsigned* __restrict__ oyu,
    const unsigned* __restrict__ xbf,
    const unsigned* __restrict__ wbf, const float* __restrict__ fcb,
    float* __restrict__ out, int n)
{
    __shared__ unsigned xl[16 * 192];   // 12 KB: 16 rows x 48 uint4-slots
    const int t = threadIdx.x;
    const int row0 = blockIdx.x * 16;

#pragma unroll
    for (int i = 0; i < 12; ++i) {
        int q = t + i * 64;
        int r = q / 48, sl = q % 48;
        int gr = row0 + r; if (gr >= n) gr = n - 1;
        const unsigned* S = (sl < 16) ? oxu : ((sl < 32) ? oyu : xbf);
        int slo = (sl < 16) ? sl : ((sl < 32) ? sl - 16 : sl - 32);
        uint4 v = ((const uint4*)S)[(size_t)gr * 16 + slo];
        int dsl = sl ^ (r & 7);
        *(uint4*)&xl[r * 192 + dsl * 4] = v;
    }
    __syncthreads();

    const int c = t & 15, q4 = t >> 4;   // single wave: rows 0..15
    f32x4 acc[3];
#pragma unroll
    for (int nt = 0; nt < 3; ++nt) acc[nt] = (f32x4){0.f, 0.f, 0.f, 0.f};

#pragma unroll
    for (int ks = 0; ks < 12; ++ks) {
        int gslot = ks * 4 + q4;
        int slot = gslot ^ (c & 7);
        s16x8 af = *(const s16x8*)&xl[c * 192 + slot * 4];
#pragma unroll
        for (int nt = 0; nt < 3; ++nt) {
            int wr = nt * 16 + c;
            s16x8 bfr = *(const s16x8*)&wbf[(size_t)wr * 192 + gslot * 4];
            acc[nt] = __builtin_amdgcn_mfma_f32_16x16x32_bf16(af, bfr, acc[nt], 0, 0, 0);
        }
    }

    float vb[3];
#pragma unroll
    for (int nt = 0; nt < 3; ++nt) {
        int col = nt * 16 + c;
        vb[nt] = (col < 40) ? fcb[col] : 0.f;
    }
    const int grow0 = row0 + q4 * 4;
#pragma unroll
    for (int j = 0; j < 4; ++j) {
        float v0 = acc[0][j] + vb[0];
        float v1 = acc[1][j] + vb[1];
        float v2 = (c < 8) ? (acc[2][j] + vb[2]) : -INFINITY;
        float m0 = fmaxf(fmaxf(v0, v1), v2);
#pragma unroll
        for (int o = 1; o < 16; o <<= 1) m0 = fmaxf(m0, __shfl_xor(m0, o));
        float s0 = __expf(v0 - m0) + __expf(v1 - m0) + ((c < 8) ? __expf(v2 - m0) : 0.f);
#pragma unroll
        for (int o = 1; o < 16; o <<= 1) s0 += __shfl_xor(s0, o);
        float lse = m0 + logf(s0);
        int grow = grow0 + j;
        if (grow < n) {
            out[(size_t)grow * 40 + c] = v0 - lse;
            out[(size_t)grow * 40 + 16 + c] = v1 - lse;
            if (c < 8) out[(size_t)grow * 40 + 32 + c] = v2 - lse;
        }
    }
}

extern "C" void kernel_launch(void* const* d_in, const int* in_sizes, int n_in,
                              void* d_out, int out_size, void* d_ws, size_t ws_size,
                              hipStream_t stream)
{
    const float* x    = (const float*)d_in[0];
    const float* y    = (const float*)d_in[1];
    const int*   eix  = (const int*)d_in[2];
    const int*   eiy  = (const int*)d_in[3];
    const float* a1iw = (const float*)d_in[4];
    const float* a1ib = (const float*)d_in[5];
    const float* a1ow = (const float*)d_in[6];
    const float* a1ob = (const float*)d_in[7];
    const float* a2iw = (const float*)d_in[8];
    const float* a2ib = (const float*)d_in[9];
    const float* a2ow = (const float*)d_in[10];
    const float* a2ob = (const float*)d_in[11];
    const float* g1w  = (const float*)d_in[12];
    const float* g1as = (const float*)d_in[13];
    const float* g1ad = (const float*)d_in[14];
    const float* g1b  = (const float*)d_in[15];
    const float* g2xw = (const float*)d_in[16];
    const float* g2xas= (const float*)d_in[17];
    const float* g2xad= (const float*)d_in[18];
    const float* g2xb = (const float*)d_in[19];
    const float* g2yw = (const float*)d_in[20];
    const float* g2yas= (const float*)d_in[21];
    const float* g2yad= (const float*)d_in[22];
    const float* g2yb = (const float*)d_in[23];
    const float* fcw  = (const float*)d_in[24];
    const float* fcb  = (const float*)d_in[25];
    float* outp = (float*)d_out;

    const int N = in_sizes[0] / 128;
    const int E = in_sizes[2] / 2;
    (void)n_in; (void)out_size; (void)ws_size;

    size_t NU = (size_t)N * 64;              // uints per packed node buffer
    unsigned* u0 = (unsigned*)d_ws;          // r1x -> ox  (bf16 packed)
    unsigned* u1 = u0 + NU;                  // hx (fp8, N*32 used)
    unsigned* u2 = u1 + NU;                  // r1y -> oy  (bf16 packed)
    unsigned* u3 = u2 + NU;                  // hy (fp8, N*32 used)
    unsigned* u4 = u3 + NU;                  // x residual, bf16 packed
    float* ssx = (float*)(u4 + NU);
    float* sdx = ssx + N;
    float* ssy = sdx + N;
    float* sdy = ssy + N;
    float* cw1 = sdy + N;
    float* cb1 = cw1 + 128 * 128;
    float* cw2 = cb1 + 128;
    float* cb2 = cw2 + 128 * 128;
    const int Npad = (N + 4) & ~3;
    int* offx = (int*)(cb2 + 128);           // N+1
    int* offy = offx + Npad;
    int* bbx  = offy + Npad;                 // nbk+1 (<=65), pad 128
    int* bby  = bbx + 128;
    int* bcx  = bby + 128;                   // 64
    int* bcy  = bcx + 64;
    int* curx = bcy + 64;                    // 64
    int* cury = curx + 64;
    unsigned* pkx = (unsigned*)(cury + 64);  // E+N packed entries
    unsigned* pky = pkx + (E + N);
    unsigned short* csx = (unsigned short*)(pky + (E + N));   // E+N ushort
    unsigned short* csy = csx + (((E + N) + 1) & ~1);
    unsigned* wbf = (unsigned*)(csy + (((E + N) + 1) & ~1));  // 48*192 uints
    float* w1cx = (float*)(wbf + 48 * 192);  // 16384 (fused GAT1 weight, x)
    float* b1cx = w1cx + 16384;              // 128
    float* w1cy = b1cx + 128;                // 16384
    float* b1cy = w1cy + 16384;              // 128
    unsigned* wpk = (unsigned*)(b1cy + 128); // 4*8192 uints (bf16 weights)

    const int ET = E + N;
    const int NBK = (N + RPB - 1) >> LOG_R;  // <= 64 required (N <= 65536)
    const int gG = (N + 63) / 64;
    const int gA = (N + 15) / 16;
    const int nAB = (ET + EPB - 1) / EPB;

    mha_combine2<<<128, 256, 0, stream>>>(a1iw, a1ib, a1ow, a1ob,
                                          a2iw, a2ib, a2ow, a2ob,
                                          cw1, cb1, cw2, cb2);
    wcomb2<<<128, 256, 0, stream>>>(g1w, cw1, cb1, cw2, cb2,
                                    w1cx, b1cx, w1cy, b1cy);
    wpack4<<<128, 256, 0, stream>>>(w1cx, w1cy, g2xw, g2yw, wpk);
    fcw_prep<<<(48 * 192 + 255) / 256, 256, 0, stream>>>(fcw, wbf, bcx);

    // ---- build both CSRs (two-level bucket sort) ----
    hist_bucket2<<<256, 256, 0, stream>>>(eix, eiy, E, N, bcx, bcy, 128);
    bscan<<<1, 128, 0, stream>>>(bcx, bcy, NBK, bbx, bby, curx, cury, offx + N, offy + N);
    bucket_pass<<<2 * nAB, 256, 0, stream>>>(eix, eiy, E, N, curx, cury, pkx, pky, nAB);
    fine_sort<<<2 * NBK, 256, 0, stream>>>(pkx, pky, bbx, bby, offx, offy, csx, csy, N, NBK);

    // ---- fused MHA+GAT1 GEMM (both): x f32 -> fp8 h (+ x saved as bf16) ----
    gemm_mfma2<false><<<2 * gG, 256, 0, stream>>>(
        x, y, wpk, wpk + 8192, b1cx, b1cy,
        g1as, g1ad, g1as, g1ad,
        (unsigned char*)u1, (unsigned char*)u3,
        ssx, sdx, ssy, sdy,
        u4, nullptr, N, gG);
    gat_aggregate2<<<2 * gA, 256, 0, stream>>>(
        offx, csx, ssx, sdx, (const unsigned char*)u1, g1b, u0,
        offy, csy, ssy, sdy, (const unsigned char*)u3, g1b, u2,
        N, 1, gA);

    // ---- GAT layer 2 (both) ----
    gemm_mfma2<true><<<2 * gG, 256, 0, stream>>>(
        u0, u2, wpk + 2 * 8192, wpk + 3 * 8192, nullptr, nullptr,
        g2xas, g2xad, g2yas, g2yad,
        (unsigned char*)u1, (unsigned char*)u3,
        ssx, sdx, ssy, sdy,
        nullptr, nullptr, N, gG);
    gat_aggregate2<<<2 * gA, 256, 0, stream>>>(
        offx, csx, ssx, sdx, (const unsigned char*)u1, g2xb, u0,
        offy, csy, ssy, sdy, (const unsigned char*)u3, g2yb, u2,
        N, 0, gA);

    // ---- fusion fc + log_softmax (MFMA, 16 rows/block) ----
    fc_logsoftmax<<<(N + 15) / 16, 64, 0, stream>>>(u0, u2, u4, wbf, fcb, outp, N);
}